// Round 1
// baseline (1532.813 us; speedup 1.0000x reference)
//
#include <hip/hip_runtime.h>
#include <math.h>

#define FEAT 64
#define BN_EPS 1e-5f

// ---------------------------------------------------------------------------
// edge_index dtype detection: reference says int64, but if the harness's JAX
// has x64 disabled it arrives as int32. For int64 (values < 50000, >= 0) the
// high 32-bit words are all zero; for int32 random indices the odd words are
// random in [0,50000). Check 64 odd words -> false positive prob ~ (2e-5)^64.
// ---------------------------------------------------------------------------
__global__ void detect_idx64_kernel(const unsigned* __restrict__ w, int* flag) {
    if (threadIdx.x == 0) {
        int all0 = 1;
        for (int i = 1; i < 128; i += 2) all0 &= (w[i] == 0u);
        *flag = all0;
    }
}

__device__ __forceinline__ int edge_idx(const void* p, int is64, long long i) {
    return is64 ? (int)((const long long*)p)[i] : ((const int*)p)[i];
}

// deg[i] = 1.0 (self loop) then atomic += ew over edges
__global__ void init_deg_kernel(float* __restrict__ deg, int N) {
    int i = blockIdx.x * 256 + threadIdx.x;
    if (i < N) deg[i] = 1.0f;
}

__global__ void accum_deg_kernel(const void* __restrict__ ei,
                                 const float* __restrict__ ew,
                                 const int* __restrict__ flag,
                                 float* __restrict__ deg, int E) {
    int e = blockIdx.x * 256 + threadIdx.x;
    if (e < E) {
        int dst = edge_idx(ei, *flag, (long long)E + e);
        unsafeAtomicAdd(&deg[dst], ew[e]);
    }
}

__global__ void deg_to_inv_kernel(const float* __restrict__ deg,
                                  float* __restrict__ dinv,
                                  float* __restrict__ invdeg, int N) {
    int i = blockIdx.x * 256 + threadIdx.x;
    if (i < N) {
        float d = deg[i];
        dinv[i]   = rsqrtf(d);
        invdeg[i] = 1.0f / d;
    }
}

__global__ void zero_sums_kernel(float* __restrict__ sums) {
    sums[threadIdx.x] = 0.0f;  // 256 floats: sum1, sq1, sum2, sq2
}

// ---------------------------------------------------------------------------
// out[i][c] = sum_k in'[i][k] * W[k][c],  in' = affine? relu(in*a+s) : in
// 256 threads = 4 rows/iter x 64 cols, 16 rows per block. W staged in LDS.
// ---------------------------------------------------------------------------
__global__ __launch_bounds__(256) void gemm64_kernel(
    const float* __restrict__ in, const float* __restrict__ W,
    const float* __restrict__ scale, const float* __restrict__ shift,
    float* __restrict__ out, int N, int affine) {
    __shared__ float Ws[64 * 64];
    __shared__ float xs[4][64];
    __shared__ float sA[64], sS[64];
    int tid = threadIdx.x;
    for (int j = tid; j < 64 * 64; j += 256) Ws[j] = W[j];
    if (affine && tid < 64) { sA[tid] = scale[tid]; sS[tid] = shift[tid]; }
    __syncthreads();
    int lr = tid >> 6, c = tid & 63;
    int rowBase = blockIdx.x * 16;
    for (int it = 0; it < 4; ++it) {
        int row = rowBase + it * 4 + lr;
        float v = 0.0f;
        if (row < N) {
            v = in[(size_t)row * 64 + c];
            if (affine) v = fmaxf(fmaf(v, sA[c], sS[c]), 0.0f);
        }
        xs[lr][c] = v;
        __syncthreads();
        if (row < N) {
            float acc = 0.0f;
#pragma unroll
            for (int k = 0; k < 64; ++k)
                acc = fmaf(xs[lr][k], Ws[k * 64 + c], acc);
            out[(size_t)row * 64 + c] = acc;
        }
        __syncthreads();
    }
}

// agg[i][c] = h[i][c] * invdeg[i] + bias[c]   (self-loop + bias, inits agg)
__global__ void agg_init_kernel(const float* __restrict__ h,
                                const float* __restrict__ invdeg,
                                const float* __restrict__ bias,
                                float* __restrict__ agg, int N) {
    int gid = blockIdx.x * 256 + threadIdx.x;
    if (gid < N * 64) {
        int i = gid >> 6, c = gid & 63;
        agg[gid] = fmaf(h[gid], invdeg[i], bias[c]);
    }
}

// 16 threads/edge, float4 gather of h[src], 4 atomic f32 adds into agg[dst]
__global__ __launch_bounds__(256) void edge_scatter_kernel(
    const void* __restrict__ ei, const float* __restrict__ ew,
    const int* __restrict__ flag, const float* __restrict__ dinv,
    const float* __restrict__ h, float* __restrict__ agg, int E) {
    long long gid = (long long)blockIdx.x * 256 + threadIdx.x;
    int e = (int)(gid >> 4);
    int sub = (int)(gid & 15);
    if (e < E) {
        int is64 = *flag;
        int src = edge_idx(ei, is64, e);
        int dst = edge_idx(ei, is64, (long long)E + e);
        float nrm = dinv[src] * ew[e] * dinv[dst];
        float4 hv = ((const float4*)(h + (size_t)src * 64))[sub];
        float* p = agg + (size_t)dst * 64 + sub * 4;
        unsafeAtomicAdd(p + 0, nrm * hv.x);
        unsafeAtomicAdd(p + 1, nrm * hv.y);
        unsafeAtomicAdd(p + 2, nrm * hv.z);
        unsafeAtomicAdd(p + 3, nrm * hv.w);
    }
}

// per-feature sum / sumsq over rows
__global__ __launch_bounds__(256) void bn_stats_kernel(
    const float* __restrict__ h, float* __restrict__ sum,
    float* __restrict__ sumsq, int N) {
    __shared__ float sS[4][64], sQ[4][64];
    int tid = threadIdx.x;
    int lr = tid >> 6, c = tid & 63;
    float s = 0.0f, q = 0.0f;
    for (int row = blockIdx.x * 4 + lr; row < N; row += gridDim.x * 4) {
        float v = h[(size_t)row * 64 + c];
        s += v;
        q += v * v;
    }
    sS[lr][c] = s;
    sQ[lr][c] = q;
    __syncthreads();
    if (tid < 64) {
        float ts = sS[0][tid] + sS[1][tid] + sS[2][tid] + sS[3][tid];
        float tq = sQ[0][tid] + sQ[1][tid] + sQ[2][tid] + sQ[3][tid];
        unsafeAtomicAdd(&sum[tid], ts);
        unsafeAtomicAdd(&sumsq[tid], tq);
    }
}

// a[c] = gamma*rsqrt(var+eps); s[c] = beta - mean*a
__global__ void bn_final_kernel(const float* __restrict__ sum,
                                const float* __restrict__ sumsq,
                                const float* __restrict__ gamma,
                                const float* __restrict__ beta,
                                float* __restrict__ a, float* __restrict__ s,
                                float invN) {
    int c = threadIdx.x;
    if (c < 64) {
        float m = sum[c] * invN;
        float var = fmaxf(sumsq[c] * invN - m * m, 0.0f);
        float aa = gamma[c] * rsqrtf(var + BN_EPS);
        a[c] = aa;
        s[c] = beta[c] - m * aa;
    }
}

// out = relu(agg*a + s + x)
__global__ void final_out_kernel(const float* __restrict__ agg,
                                 const float* __restrict__ a,
                                 const float* __restrict__ s,
                                 const float* __restrict__ x,
                                 float* __restrict__ out, int total) {
    int gid = blockIdx.x * 256 + threadIdx.x;
    if (gid < total) {
        int c = gid & 63;
        out[gid] = fmaxf(fmaf(agg[gid], a[c], s[c]) + x[gid], 0.0f);
    }
}

extern "C" void kernel_launch(void* const* d_in, const int* in_sizes, int n_in,
                              void* d_out, int out_size, void* d_ws, size_t ws_size,
                              hipStream_t stream) {
    const float* x      = (const float*)d_in[0];
    const void*  ei     = d_in[1];           // int64 or int32, detected on device
    const float* ew     = (const float*)d_in[2];
    const float* W1     = (const float*)d_in[3];
    const float* b1     = (const float*)d_in[4];
    const float* gamma1 = (const float*)d_in[5];
    const float* beta1  = (const float*)d_in[6];
    const float* W2     = (const float*)d_in[7];
    const float* b2     = (const float*)d_in[8];
    const float* gamma2 = (const float*)d_in[9];
    const float* beta2  = (const float*)d_in[10];
    float* out = (float*)d_out;

    const int N = in_sizes[0] / FEAT;
    const int E = in_sizes[2];

    // workspace layout (256B-aligned chunks)
    char* ws = (char*)d_ws;
    size_t off = 0;
    auto alloc = [&](size_t bytes) {
        size_t o = off;
        off += (bytes + 255) & ~(size_t)255;
        return (void*)(ws + o);
    };
    int*   flag   = (int*)  alloc(256);
    float* deg    = (float*)alloc((size_t)N * 4);
    float* dinv   = (float*)alloc((size_t)N * 4);
    float* invdeg = (float*)alloc((size_t)N * 4);
    float* sums   = (float*)alloc(256 * 4);   // sum1[64] sq1[64] sum2[64] sq2[64]
    float* ab     = (float*)alloc(256 * 4);   // a1[64] s1[64] a2[64] s2[64]
    float* h      = (float*)alloc((size_t)N * FEAT * 4);
    float* agg    = (float*)alloc((size_t)N * FEAT * 4);

    const int nblkN  = (N + 255) / 256;
    const int nblkE  = (E + 255) / 256;
    const int nblkNF = (N * FEAT + 255) / 256;
    const int nblkG  = (N + 15) / 16;
    const int nblkE16 = (int)(((long long)E * 16 + 255) / 256);

    detect_idx64_kernel<<<1, 64, 0, stream>>>((const unsigned*)ei, flag);
    init_deg_kernel<<<nblkN, 256, 0, stream>>>(deg, N);
    accum_deg_kernel<<<nblkE, 256, 0, stream>>>(ei, ew, flag, deg, E);
    deg_to_inv_kernel<<<nblkN, 256, 0, stream>>>(deg, dinv, invdeg, N);
    zero_sums_kernel<<<1, 256, 0, stream>>>(sums);

    // ---- layer 1 ----
    gemm64_kernel<<<nblkG, 256, 0, stream>>>(x, W1, nullptr, nullptr, h, N, 0);
    agg_init_kernel<<<nblkNF, 256, 0, stream>>>(h, invdeg, b1, agg, N);
    edge_scatter_kernel<<<nblkE16, 256, 0, stream>>>(ei, ew, flag, dinv, h, agg, E);
    bn_stats_kernel<<<256, 256, 0, stream>>>(agg, sums, sums + 64, N);
    bn_final_kernel<<<1, 64, 0, stream>>>(sums, sums + 64, gamma1, beta1,
                                          ab, ab + 64, 1.0f / (float)N);

    // ---- layer 2 (gemm fuses BN1 apply + relu on input load) ----
    gemm64_kernel<<<nblkG, 256, 0, stream>>>(agg, W2, ab, ab + 64, h, N, 1);
    agg_init_kernel<<<nblkNF, 256, 0, stream>>>(h, invdeg, b2, agg, N);
    edge_scatter_kernel<<<nblkE16, 256, 0, stream>>>(ei, ew, flag, dinv, h, agg, E);
    bn_stats_kernel<<<256, 256, 0, stream>>>(agg, sums + 128, sums + 192, N);
    bn_final_kernel<<<1, 64, 0, stream>>>(sums + 128, sums + 192, gamma2, beta2,
                                          ab + 128, ab + 192, 1.0f / (float)N);

    // ---- residual + relu ----
    final_out_kernel<<<nblkNF, 256, 0, stream>>>(agg, ab + 128, ab + 192, x,
                                                 out, N * FEAT);
}

// Round 2
// 395.644 us; speedup vs baseline: 3.8742x; 3.8742x over previous
//
#include <hip/hip_runtime.h>
#include <math.h>

#define FEAT 64
#define BN_EPS 1e-5f

// ---------------------------------------------------------------------------
// edge_index dtype detection: reference says int64, but if the harness's JAX
// has x64 disabled it arrives as int32. For int64 (values < 50000, >= 0) the
// high 32-bit words are all zero; for int32 random indices the odd words are
// random in [0,50000). Check 64 odd words -> false positive prob ~ (2e-5)^64.
// ---------------------------------------------------------------------------
__global__ void detect_idx64_kernel(const unsigned* __restrict__ w, int* flag) {
    if (threadIdx.x == 0) {
        int all0 = 1;
        for (int i = 1; i < 128; i += 2) all0 &= (w[i] == 0u);
        *flag = all0;
    }
}

__device__ __forceinline__ int edge_idx(const void* p, int is64, long long i) {
    return is64 ? (int)((const long long*)p)[i] : ((const int*)p)[i];
}

// deg[i] = 1.0 (self loop), cnt[i] = 0
__global__ void init_nodes_kernel(float* __restrict__ deg, int* __restrict__ cnt, int N) {
    int i = blockIdx.x * 256 + threadIdx.x;
    if (i < N) { deg[i] = 1.0f; cnt[i] = 0; }
}

// count edges per dst + accumulate weighted degree
__global__ void count_deg_kernel(const void* __restrict__ ei,
                                 const float* __restrict__ ew,
                                 const int* __restrict__ flag,
                                 int* __restrict__ cnt,
                                 float* __restrict__ deg, int E) {
    int e = blockIdx.x * 256 + threadIdx.x;
    if (e < E) {
        int dst = edge_idx(ei, *flag, (long long)E + e);
        atomicAdd(&cnt[dst], 1);
        unsafeAtomicAdd(&deg[dst], ew[e]);
    }
}

__global__ void deg_to_inv_kernel(const float* __restrict__ deg,
                                  float* __restrict__ dinv,
                                  float* __restrict__ invdeg, int N) {
    int i = blockIdx.x * 256 + threadIdx.x;
    if (i < N) {
        float d = deg[i];
        dinv[i]   = rsqrtf(d);
        invdeg[i] = 1.0f / d;
    }
}

// ---- exclusive scan over cnt[N] -> rowptr (3-level; N <= 256*256) ----------
__global__ __launch_bounds__(256) void scan1_kernel(const int* __restrict__ cnt,
                                                    int* __restrict__ excl,
                                                    int* __restrict__ bsum, int N) {
    __shared__ int tmp[256];
    int i = blockIdx.x * 256 + threadIdx.x;
    int v = (i < N) ? cnt[i] : 0;
    tmp[threadIdx.x] = v;
    __syncthreads();
    for (int off = 1; off < 256; off <<= 1) {
        int t = (threadIdx.x >= off) ? tmp[threadIdx.x - off] : 0;
        __syncthreads();
        tmp[threadIdx.x] += t;
        __syncthreads();
    }
    if (i < N) excl[i] = tmp[threadIdx.x] - v;
    if (threadIdx.x == 255) bsum[blockIdx.x] = tmp[255];
}

__global__ __launch_bounds__(256) void scan2_kernel(int* __restrict__ bsum, int nb) {
    __shared__ int tmp[256];
    int i = threadIdx.x;
    int v = (i < nb) ? bsum[i] : 0;
    tmp[i] = v;
    __syncthreads();
    for (int off = 1; off < 256; off <<= 1) {
        int t = (i >= off) ? tmp[i - off] : 0;
        __syncthreads();
        tmp[i] += t;
        __syncthreads();
    }
    if (i < nb) bsum[i] = tmp[i] - v;  // exclusive block offsets, in place
}

__global__ void scan3_kernel(const int* __restrict__ excl,
                             const int* __restrict__ bsum,
                             int* __restrict__ rowptr,
                             int* __restrict__ cursor, int N, int E) {
    int i = blockIdx.x * 256 + threadIdx.x;
    if (i < N) {
        int r = excl[i] + bsum[blockIdx.x];
        rowptr[i] = r;
        cursor[i] = r;
    }
    if (i == 0) rowptr[N] = E;
}

// scatter edges into CSR slots: csr[pos] = (src, norm-bits)
__global__ void scatter_csr_kernel(const void* __restrict__ ei,
                                   const float* __restrict__ ew,
                                   const int* __restrict__ flag,
                                   const float* __restrict__ dinv,
                                   int* __restrict__ cursor,
                                   int2* __restrict__ csr, int E) {
    int e = blockIdx.x * 256 + threadIdx.x;
    if (e < E) {
        int is64 = *flag;
        int src = edge_idx(ei, is64, e);
        int dst = edge_idx(ei, is64, (long long)E + e);
        float nrm = dinv[src] * ew[e] * dinv[dst];
        int pos = atomicAdd(&cursor[dst], 1);
        csr[pos] = make_int2(src, __float_as_int(nrm));
    }
}

__global__ void zero_sums_kernel(float* __restrict__ sums) {
    sums[threadIdx.x] = 0.0f;  // 256 floats: sum1, sq1, sum2, sq2
}

// ---------------------------------------------------------------------------
// out[i][c] = sum_k in'[i][k] * W[k][c],  in' = affine? relu(in*a+s) : in
// ---------------------------------------------------------------------------
__global__ __launch_bounds__(256) void gemm64_kernel(
    const float* __restrict__ in, const float* __restrict__ W,
    const float* __restrict__ scale, const float* __restrict__ shift,
    float* __restrict__ out, int N, int affine) {
    __shared__ float Ws[64 * 64];
    __shared__ float xs[4][64];
    __shared__ float sA[64], sS[64];
    int tid = threadIdx.x;
    for (int j = tid; j < 64 * 64; j += 256) Ws[j] = W[j];
    if (affine && tid < 64) { sA[tid] = scale[tid]; sS[tid] = shift[tid]; }
    __syncthreads();
    int lr = tid >> 6, c = tid & 63;
    int rowBase = blockIdx.x * 16;
    for (int it = 0; it < 4; ++it) {
        int row = rowBase + it * 4 + lr;
        float v = 0.0f;
        if (row < N) {
            v = in[(size_t)row * 64 + c];
            if (affine) v = fmaxf(fmaf(v, sA[c], sS[c]), 0.0f);
        }
        xs[lr][c] = v;
        __syncthreads();
        if (row < N) {
            float acc = 0.0f;
#pragma unroll
            for (int k = 0; k < 64; ++k)
                acc = fmaf(xs[lr][k], Ws[k * 64 + c], acc);
            out[(size_t)row * 64 + c] = acc;
        }
        __syncthreads();
    }
}

// ---------------------------------------------------------------------------
// Gather-side aggregation (replaces agg_init + atomic edge scatter):
// agg[n][c] = h[n][c]*invdeg[n] + bias[c] + sum_{k in [rowptr[n],rowptr[n+1])}
//             norm[k] * h[src[k]][c]
// 256 threads = 4 nodes x 64 features.
// ---------------------------------------------------------------------------
__global__ __launch_bounds__(256) void gather_agg_kernel(
    const float* __restrict__ h, const int* __restrict__ rowptr,
    const int2* __restrict__ csr, const float* __restrict__ invdeg,
    const float* __restrict__ bias, float* __restrict__ agg, int N) {
    int tid = threadIdx.x;
    int lr = tid >> 6, c = tid & 63;
    int n = blockIdx.x * 4 + lr;
    if (n < N) {
        int beg = rowptr[n], end = rowptr[n + 1];
        float acc = fmaf(h[(size_t)n * 64 + c], invdeg[n], bias[c]);
        for (int k = beg; k < end; ++k) {
            int2 ed = csr[k];  // broadcast across the 64-thread group
            acc = fmaf(__int_as_float(ed.y), h[(size_t)ed.x * 64 + c], acc);
        }
        agg[(size_t)n * 64 + c] = acc;
    }
}

// per-feature sum / sumsq over rows
__global__ __launch_bounds__(256) void bn_stats_kernel(
    const float* __restrict__ h, float* __restrict__ sum,
    float* __restrict__ sumsq, int N) {
    __shared__ float sS[4][64], sQ[4][64];
    int tid = threadIdx.x;
    int lr = tid >> 6, c = tid & 63;
    float s = 0.0f, q = 0.0f;
    for (int row = blockIdx.x * 4 + lr; row < N; row += gridDim.x * 4) {
        float v = h[(size_t)row * 64 + c];
        s += v;
        q += v * v;
    }
    sS[lr][c] = s;
    sQ[lr][c] = q;
    __syncthreads();
    if (tid < 64) {
        float ts = sS[0][tid] + sS[1][tid] + sS[2][tid] + sS[3][tid];
        float tq = sQ[0][tid] + sQ[1][tid] + sQ[2][tid] + sQ[3][tid];
        unsafeAtomicAdd(&sum[tid], ts);
        unsafeAtomicAdd(&sumsq[tid], tq);
    }
}

// a[c] = gamma*rsqrt(var+eps); s[c] = beta - mean*a
__global__ void bn_final_kernel(const float* __restrict__ sum,
                                const float* __restrict__ sumsq,
                                const float* __restrict__ gamma,
                                const float* __restrict__ beta,
                                float* __restrict__ a, float* __restrict__ s,
                                float invN) {
    int c = threadIdx.x;
    if (c < 64) {
        float m = sum[c] * invN;
        float var = fmaxf(sumsq[c] * invN - m * m, 0.0f);
        float aa = gamma[c] * rsqrtf(var + BN_EPS);
        a[c] = aa;
        s[c] = beta[c] - m * aa;
    }
}

// out = relu(agg*a + s + x)
__global__ void final_out_kernel(const float* __restrict__ agg,
                                 const float* __restrict__ a,
                                 const float* __restrict__ s,
                                 const float* __restrict__ x,
                                 float* __restrict__ out, int total) {
    int gid = blockIdx.x * 256 + threadIdx.x;
    if (gid < total) {
        int c = gid & 63;
        out[gid] = fmaxf(fmaf(agg[gid], a[c], s[c]) + x[gid], 0.0f);
    }
}

extern "C" void kernel_launch(void* const* d_in, const int* in_sizes, int n_in,
                              void* d_out, int out_size, void* d_ws, size_t ws_size,
                              hipStream_t stream) {
    const float* x      = (const float*)d_in[0];
    const void*  ei     = d_in[1];           // int64 or int32, detected on device
    const float* ew     = (const float*)d_in[2];
    const float* W1     = (const float*)d_in[3];
    const float* b1     = (const float*)d_in[4];
    const float* gamma1 = (const float*)d_in[5];
    const float* beta1  = (const float*)d_in[6];
    const float* W2     = (const float*)d_in[7];
    const float* b2     = (const float*)d_in[8];
    const float* gamma2 = (const float*)d_in[9];
    const float* beta2  = (const float*)d_in[10];
    float* out = (float*)d_out;

    const int N = in_sizes[0] / FEAT;
    const int E = in_sizes[2];

    // workspace layout (256B-aligned chunks)
    char* ws = (char*)d_ws;
    size_t off = 0;
    auto alloc = [&](size_t bytes) {
        size_t o = off;
        off += (bytes + 255) & ~(size_t)255;
        return (void*)(ws + o);
    };
    int*   flag   = (int*)  alloc(256);
    int*   cnt    = (int*)  alloc((size_t)N * 4);
    int*   rowptr = (int*)  alloc((size_t)(N + 1) * 4);
    int*   cursor = (int*)  alloc((size_t)N * 4);
    int*   excl   = (int*)  alloc((size_t)N * 4);
    int*   bsum   = (int*)  alloc(256 * 4);
    float* deg    = (float*)alloc((size_t)N * 4);
    float* dinv   = (float*)alloc((size_t)N * 4);
    float* invdeg = (float*)alloc((size_t)N * 4);
    float* sums   = (float*)alloc(256 * 4);   // sum1[64] sq1[64] sum2[64] sq2[64]
    float* ab     = (float*)alloc(256 * 4);   // a1[64] s1[64] a2[64] s2[64]
    int2*  csr    = (int2*) alloc((size_t)E * 8);
    float* h      = (float*)alloc((size_t)N * FEAT * 4);
    float* agg    = (float*)alloc((size_t)N * FEAT * 4);

    const int nblkN  = (N + 255) / 256;
    const int nblkE  = (E + 255) / 256;
    const int nblkNF = (N * FEAT + 255) / 256;
    const int nblkG  = (N + 15) / 16;
    const int nblkA  = (N + 3) / 4;

    // ---- CSR build (shared by both layers) ----
    detect_idx64_kernel<<<1, 64, 0, stream>>>((const unsigned*)ei, flag);
    init_nodes_kernel<<<nblkN, 256, 0, stream>>>(deg, cnt, N);
    count_deg_kernel<<<nblkE, 256, 0, stream>>>(ei, ew, flag, cnt, deg, E);
    deg_to_inv_kernel<<<nblkN, 256, 0, stream>>>(deg, dinv, invdeg, N);
    scan1_kernel<<<nblkN, 256, 0, stream>>>(cnt, excl, bsum, N);
    scan2_kernel<<<1, 256, 0, stream>>>(bsum, nblkN);
    scan3_kernel<<<nblkN, 256, 0, stream>>>(excl, bsum, rowptr, cursor, N, E);
    scatter_csr_kernel<<<nblkE, 256, 0, stream>>>(ei, ew, flag, dinv, cursor, csr, E);
    zero_sums_kernel<<<1, 256, 0, stream>>>(sums);

    // ---- layer 1 ----
    gemm64_kernel<<<nblkG, 256, 0, stream>>>(x, W1, nullptr, nullptr, h, N, 0);
    gather_agg_kernel<<<nblkA, 256, 0, stream>>>(h, rowptr, csr, invdeg, b1, agg, N);
    bn_stats_kernel<<<256, 256, 0, stream>>>(agg, sums, sums + 64, N);
    bn_final_kernel<<<1, 64, 0, stream>>>(sums, sums + 64, gamma1, beta1,
                                          ab, ab + 64, 1.0f / (float)N);

    // ---- layer 2 (gemm fuses BN1 apply + relu on input load) ----
    gemm64_kernel<<<nblkG, 256, 0, stream>>>(agg, W2, ab, ab + 64, h, N, 1);
    gather_agg_kernel<<<nblkA, 256, 0, stream>>>(h, rowptr, csr, invdeg, b2, agg, N);
    bn_stats_kernel<<<256, 256, 0, stream>>>(agg, sums + 128, sums + 192, N);
    bn_final_kernel<<<1, 64, 0, stream>>>(sums + 128, sums + 192, gamma2, beta2,
                                          ab + 128, ab + 192, 1.0f / (float)N);

    // ---- residual + relu ----
    final_out_kernel<<<nblkNF, 256, 0, stream>>>(agg, ab + 128, ab + 192, x,
                                                 out, N * FEAT);
}

// Round 3
// 336.402 us; speedup vs baseline: 4.5565x; 1.1761x over previous
//
#include <hip/hip_runtime.h>
#include <math.h>

#define FEAT 64
#define BN_EPS 1e-5f

__device__ __forceinline__ int edge_idx(const void* p, int is64, long long i) {
    return is64 ? (int)((const long long*)p)[i] : ((const int*)p)[i];
}

// ---------------------------------------------------------------------------
// init: cnt[i]=0; block 0 also zeroes BN sums and detects edge_index dtype.
// dtype detect: int64 values < 50000 have all-zero high words; int32 random
// indices make the odd 32-bit words nonzero. 64 odd words -> fp prob ~1e-300.
// ---------------------------------------------------------------------------
__global__ __launch_bounds__(256) void init_kernel(
    const unsigned* __restrict__ w, int* __restrict__ flag,
    int* __restrict__ cnt, float* __restrict__ sums, int N) {
    int i = blockIdx.x * 256 + threadIdx.x;
    if (i < N) cnt[i] = 0;
    if (blockIdx.x == 0) {
        sums[threadIdx.x] = 0.0f;                    // 256: sum1 sq1 sum2 sq2
        if (threadIdx.x < 64) {
            unsigned long long ok = __ballot(w[2 * threadIdx.x + 1] == 0u);
            if (threadIdx.x == 0) *flag = (ok == ~0ull);
        }
    }
}

// count edges per dst; seq[e] = arrival slot within its dst row (the atomic's
// return value). 4 independent atomics in flight per thread.
__global__ __launch_bounds__(256) void count_seq_kernel(
    const void* __restrict__ ei, const int* __restrict__ flag,
    int* __restrict__ cnt, int* __restrict__ seq, int E) {
    int is64 = *flag;
    int T = gridDim.x * 256;
    int i = blockIdx.x * 256 + threadIdx.x;
#pragma unroll
    for (int u = 0; u < 4; ++u) {
        int e = i + u * T;
        if (e < E) {
            int dst = edge_idx(ei, is64, (long long)E + e);
            seq[e] = atomicAdd(&cnt[dst], 1);
        }
    }
}

// ---- exclusive scan over cnt[N] -> rowptr (3-level; N <= 256*256) ----------
__global__ __launch_bounds__(256) void scan1_kernel(const int* __restrict__ cnt,
                                                    int* __restrict__ excl,
                                                    int* __restrict__ bsum, int N) {
    __shared__ int tmp[256];
    int i = blockIdx.x * 256 + threadIdx.x;
    int v = (i < N) ? cnt[i] : 0;
    tmp[threadIdx.x] = v;
    __syncthreads();
    for (int off = 1; off < 256; off <<= 1) {
        int t = (threadIdx.x >= off) ? tmp[threadIdx.x - off] : 0;
        __syncthreads();
        tmp[threadIdx.x] += t;
        __syncthreads();
    }
    if (i < N) excl[i] = tmp[threadIdx.x] - v;
    if (threadIdx.x == 255) bsum[blockIdx.x] = tmp[255];
}

__global__ __launch_bounds__(256) void scan2_kernel(int* __restrict__ bsum, int nb) {
    __shared__ int tmp[256];
    int i = threadIdx.x;
    int v = (i < nb) ? bsum[i] : 0;
    tmp[i] = v;
    __syncthreads();
    for (int off = 1; off < 256; off <<= 1) {
        int t = (i >= off) ? tmp[i - off] : 0;
        __syncthreads();
        tmp[i] += t;
        __syncthreads();
    }
    if (i < nb) bsum[i] = tmp[i] - v;  // exclusive block offsets, in place
}

__global__ void scan3_kernel(const int* __restrict__ excl,
                             const int* __restrict__ bsum,
                             int* __restrict__ rowptr, int N, int E) {
    int i = blockIdx.x * 256 + threadIdx.x;
    if (i < N) rowptr[i] = excl[i] + bsum[blockIdx.x];
    if (i == 0) rowptr[N] = E;
}

// csr[rowptr[dst]+seq[e]] = (src, ew-bits) — no atomics, plain writes
__global__ __launch_bounds__(256) void scatter_csr_kernel(
    const void* __restrict__ ei, const float* __restrict__ ew,
    const int* __restrict__ flag, const int* __restrict__ rowptr,
    const int* __restrict__ seq, int2* __restrict__ csr, int E) {
    int e = blockIdx.x * 256 + threadIdx.x;
    if (e < E) {
        int is64 = *flag;
        int src = edge_idx(ei, is64, e);
        int dst = edge_idx(ei, is64, (long long)E + e);
        int pos = rowptr[dst] + seq[e];
        csr[pos] = make_int2(src, __float_as_int(ew[e]));
    }
}

// deg[n] = 1 + sum ew over row; dinv = rsqrt, invdeg = 1/deg
__global__ void deg_inv_kernel(const int* __restrict__ rowptr,
                               const int2* __restrict__ csr,
                               float* __restrict__ dinv,
                               float* __restrict__ invdeg, int N) {
    int n = blockIdx.x * 256 + threadIdx.x;
    if (n < N) {
        int b = rowptr[n], e = rowptr[n + 1];
        float d = 1.0f;
        for (int k = b; k < e; ++k) d += __int_as_float(csr[k].y);
        dinv[n]   = rsqrtf(d);
        invdeg[n] = 1.0f / d;
    }
}

// csr[k].y: ew -> norm = dinv[src]*ew*dinv[n]
__global__ void norm_kernel(const int* __restrict__ rowptr,
                            const float* __restrict__ dinv,
                            int2* __restrict__ csr, int N) {
    int n = blockIdx.x * 256 + threadIdx.x;
    if (n < N) {
        int b = rowptr[n], e = rowptr[n + 1];
        float dn = dinv[n];
        for (int k = b; k < e; ++k) {
            int2 ed = csr[k];
            csr[k].y = __float_as_int(dinv[ed.x] * __int_as_float(ed.y) * dn);
        }
    }
}

// ---------------------------------------------------------------------------
// out[i][c] = sum_k in'[i][k] * W[k][c],  in' = affine? relu(in*a+s) : in
// ---------------------------------------------------------------------------
__global__ __launch_bounds__(256) void gemm64_kernel(
    const float* __restrict__ in, const float* __restrict__ W,
    const float* __restrict__ scale, const float* __restrict__ shift,
    float* __restrict__ out, int N, int affine) {
    __shared__ float Ws[64 * 64];
    __shared__ float xs[4][64];
    __shared__ float sA[64], sS[64];
    int tid = threadIdx.x;
    for (int j = tid; j < 64 * 64; j += 256) Ws[j] = W[j];
    if (affine && tid < 64) { sA[tid] = scale[tid]; sS[tid] = shift[tid]; }
    __syncthreads();
    int lr = tid >> 6, c = tid & 63;
    int rowBase = blockIdx.x * 16;
    for (int it = 0; it < 4; ++it) {
        int row = rowBase + it * 4 + lr;
        float v = 0.0f;
        if (row < N) {
            v = in[(size_t)row * 64 + c];
            if (affine) v = fmaxf(fmaf(v, sA[c], sS[c]), 0.0f);
        }
        xs[lr][c] = v;
        __syncthreads();
        if (row < N) {
            float acc = 0.0f;
#pragma unroll
            for (int k = 0; k < 64; ++k)
                acc = fmaf(xs[lr][k], Ws[k * 64 + c], acc);
            out[(size_t)row * 64 + c] = acc;
        }
        __syncthreads();
    }
}

// ---------------------------------------------------------------------------
// agg[n][c] = h[n][c]*invdeg[n] + bias[c] + sum_k norm[k]*h[src[k]][c]
// 256 threads = 4 nodes x 64 features.
// ---------------------------------------------------------------------------
__global__ __launch_bounds__(256) void gather_agg_kernel(
    const float* __restrict__ h, const int* __restrict__ rowptr,
    const int2* __restrict__ csr, const float* __restrict__ invdeg,
    const float* __restrict__ bias, float* __restrict__ agg, int N) {
    int tid = threadIdx.x;
    int lr = tid >> 6, c = tid & 63;
    int n = blockIdx.x * 4 + lr;
    if (n < N) {
        int beg = rowptr[n], end = rowptr[n + 1];
        float acc = fmaf(h[(size_t)n * 64 + c], invdeg[n], bias[c]);
        for (int k = beg; k < end; ++k) {
            int2 ed = csr[k];  // broadcast across the 64-thread group
            acc = fmaf(__int_as_float(ed.y), h[(size_t)ed.x * 64 + c], acc);
        }
        agg[(size_t)n * 64 + c] = acc;
    }
}

// per-feature sum / sumsq over rows
__global__ __launch_bounds__(256) void bn_stats_kernel(
    const float* __restrict__ h, float* __restrict__ sum,
    float* __restrict__ sumsq, int N) {
    __shared__ float sS[4][64], sQ[4][64];
    int tid = threadIdx.x;
    int lr = tid >> 6, c = tid & 63;
    float s = 0.0f, q = 0.0f;
    for (int row = blockIdx.x * 4 + lr; row < N; row += gridDim.x * 4) {
        float v = h[(size_t)row * 64 + c];
        s += v;
        q += v * v;
    }
    sS[lr][c] = s;
    sQ[lr][c] = q;
    __syncthreads();
    if (tid < 64) {
        float ts = sS[0][tid] + sS[1][tid] + sS[2][tid] + sS[3][tid];
        float tq = sQ[0][tid] + sQ[1][tid] + sQ[2][tid] + sQ[3][tid];
        unsafeAtomicAdd(&sum[tid], ts);
        unsafeAtomicAdd(&sumsq[tid], tq);
    }
}

// a[c] = gamma*rsqrt(var+eps); s[c] = beta - mean*a
__global__ void bn_final_kernel(const float* __restrict__ sum,
                                const float* __restrict__ sumsq,
                                const float* __restrict__ gamma,
                                const float* __restrict__ beta,
                                float* __restrict__ a, float* __restrict__ s,
                                float invN) {
    int c = threadIdx.x;
    if (c < 64) {
        float m = sum[c] * invN;
        float var = fmaxf(sumsq[c] * invN - m * m, 0.0f);
        float aa = gamma[c] * rsqrtf(var + BN_EPS);
        a[c] = aa;
        s[c] = beta[c] - m * aa;
    }
}

// out = relu(agg*a + s + x)
__global__ void final_out_kernel(const float* __restrict__ agg,
                                 const float* __restrict__ a,
                                 const float* __restrict__ s,
                                 const float* __restrict__ x,
                                 float* __restrict__ out, int total) {
    int gid = blockIdx.x * 256 + threadIdx.x;
    if (gid < total) {
        int c = gid & 63;
        out[gid] = fmaxf(fmaf(agg[gid], a[c], s[c]) + x[gid], 0.0f);
    }
}

extern "C" void kernel_launch(void* const* d_in, const int* in_sizes, int n_in,
                              void* d_out, int out_size, void* d_ws, size_t ws_size,
                              hipStream_t stream) {
    const float* x      = (const float*)d_in[0];
    const void*  ei     = d_in[1];           // int64 or int32, detected on device
    const float* ew     = (const float*)d_in[2];
    const float* W1     = (const float*)d_in[3];
    const float* b1     = (const float*)d_in[4];
    const float* gamma1 = (const float*)d_in[5];
    const float* beta1  = (const float*)d_in[6];
    const float* W2     = (const float*)d_in[7];
    const float* b2     = (const float*)d_in[8];
    const float* gamma2 = (const float*)d_in[9];
    const float* beta2  = (const float*)d_in[10];
    float* out = (float*)d_out;

    const int N = in_sizes[0] / FEAT;
    const int E = in_sizes[2];

    // workspace layout (256B-aligned chunks)
    char* ws = (char*)d_ws;
    size_t off = 0;
    auto alloc = [&](size_t bytes) {
        size_t o = off;
        off += (bytes + 255) & ~(size_t)255;
        return (void*)(ws + o);
    };
    int*   flag   = (int*)  alloc(256);
    int*   cnt    = (int*)  alloc((size_t)N * 4);
    int*   rowptr = (int*)  alloc((size_t)(N + 1) * 4);
    int*   seq    = (int*)  alloc((size_t)E * 4);
    int*   excl   = (int*)  alloc((size_t)N * 4);
    int*   bsum   = (int*)  alloc(256 * 4);
    float* dinv   = (float*)alloc((size_t)N * 4);
    float* invdeg = (float*)alloc((size_t)N * 4);
    float* sums   = (float*)alloc(256 * 4);   // sum1[64] sq1[64] sum2[64] sq2[64]
    float* ab     = (float*)alloc(256 * 4);   // a1[64] s1[64] a2[64] s2[64]
    int2*  csr    = (int2*) alloc((size_t)E * 8);
    float* h      = (float*)alloc((size_t)N * FEAT * 4);
    float* agg    = (float*)alloc((size_t)N * FEAT * 4);

    const int nblkN  = (N + 255) / 256;
    const int nblkE  = (E + 255) / 256;
    const int nblkE4 = (E + 1023) / 1024;
    const int nblkNF = (N * FEAT + 255) / 256;
    const int nblkG  = (N + 15) / 16;
    const int nblkA  = (N + 3) / 4;

    // ---- CSR build (shared by both layers; 800K atomics total) ----
    init_kernel<<<nblkN, 256, 0, stream>>>((const unsigned*)ei, flag, cnt, sums, N);
    count_seq_kernel<<<nblkE4, 256, 0, stream>>>(ei, flag, cnt, seq, E);
    scan1_kernel<<<nblkN, 256, 0, stream>>>(cnt, excl, bsum, N);
    scan2_kernel<<<1, 256, 0, stream>>>(bsum, nblkN);
    scan3_kernel<<<nblkN, 256, 0, stream>>>(excl, bsum, rowptr, N, E);
    scatter_csr_kernel<<<nblkE, 256, 0, stream>>>(ei, ew, flag, rowptr, seq, csr, E);
    deg_inv_kernel<<<nblkN, 256, 0, stream>>>(rowptr, csr, dinv, invdeg, N);
    norm_kernel<<<nblkN, 256, 0, stream>>>(rowptr, dinv, csr, N);

    // ---- layer 1 ----
    gemm64_kernel<<<nblkG, 256, 0, stream>>>(x, W1, nullptr, nullptr, h, N, 0);
    gather_agg_kernel<<<nblkA, 256, 0, stream>>>(h, rowptr, csr, invdeg, b1, agg, N);
    bn_stats_kernel<<<256, 256, 0, stream>>>(agg, sums, sums + 64, N);
    bn_final_kernel<<<1, 64, 0, stream>>>(sums, sums + 64, gamma1, beta1,
                                          ab, ab + 64, 1.0f / (float)N);

    // ---- layer 2 (gemm fuses BN1 apply + relu on input load) ----
    gemm64_kernel<<<nblkG, 256, 0, stream>>>(agg, W2, ab, ab + 64, h, N, 1);
    gather_agg_kernel<<<nblkA, 256, 0, stream>>>(h, rowptr, csr, invdeg, b2, agg, N);
    bn_stats_kernel<<<256, 256, 0, stream>>>(agg, sums + 128, sums + 192, N);
    bn_final_kernel<<<1, 64, 0, stream>>>(sums + 128, sums + 192, gamma2, beta2,
                                          ab + 128, ab + 192, 1.0f / (float)N);

    // ---- residual + relu ----
    final_out_kernel<<<nblkNF, 256, 0, stream>>>(agg, ab + 128, ab + 192, x,
                                                 out, N * FEAT);
}

// Round 4
// 242.144 us; speedup vs baseline: 6.3302x; 1.3893x over previous
//
#include <hip/hip_runtime.h>
#include <math.h>

#define FEAT 64
#define BN_EPS 1e-5f

__device__ __forceinline__ int edge_idx(const void* p, int is64, long long i) {
    return is64 ? (int)((const long long*)p)[i] : ((const int*)p)[i];
}

__device__ __forceinline__ float4 f4fma(float a, float4 b, float4 c) {
    return make_float4(fmaf(a, b.x, c.x), fmaf(a, b.y, c.y),
                       fmaf(a, b.z, c.z), fmaf(a, b.w, c.w));
}

// ---------------------------------------------------------------------------
// init: cnt[i]=0; block 0 also zeroes BN sums and detects edge_index dtype.
// dtype detect: int64 values < 50000 have all-zero high words; int32 random
// indices make the odd 32-bit words nonzero. 64 odd words -> fp prob ~1e-300.
// ---------------------------------------------------------------------------
__global__ __launch_bounds__(256) void init_kernel(
    const unsigned* __restrict__ w, int* __restrict__ flag,
    int* __restrict__ cnt, float* __restrict__ sums, int N) {
    int i = blockIdx.x * 256 + threadIdx.x;
    if (i < N) cnt[i] = 0;
    if (blockIdx.x == 0) {
        sums[threadIdx.x] = 0.0f;                    // 256: sum1 sq1 sum2 sq2
        if (threadIdx.x < 64) {
            unsigned long long ok = __ballot(w[2 * threadIdx.x + 1] == 0u);
            if (threadIdx.x == 0) *flag = (ok == ~0ull);
        }
    }
}

// count edges per dst; seq[e] = arrival slot within its dst row (the atomic's
// return value). 8 independent atomics in flight per thread.
__global__ __launch_bounds__(256) void count_seq_kernel(
    const void* __restrict__ ei, const int* __restrict__ flag,
    int* __restrict__ cnt, int* __restrict__ seq, int E) {
    int is64 = *flag;
    int T = gridDim.x * 256;
    int i = blockIdx.x * 256 + threadIdx.x;
#pragma unroll
    for (int u = 0; u < 8; ++u) {
        int e = i + u * T;
        if (e < E) {
            int dst = edge_idx(ei, is64, (long long)E + e);
            seq[e] = atomicAdd(&cnt[dst], 1);
        }
    }
}

// ---- exclusive scan over cnt[N] -> rowptr (3-level; N <= 256*256) ----------
__global__ __launch_bounds__(256) void scan1_kernel(const int* __restrict__ cnt,
                                                    int* __restrict__ excl,
                                                    int* __restrict__ bsum, int N) {
    __shared__ int tmp[256];
    int i = blockIdx.x * 256 + threadIdx.x;
    int v = (i < N) ? cnt[i] : 0;
    tmp[threadIdx.x] = v;
    __syncthreads();
    for (int off = 1; off < 256; off <<= 1) {
        int t = (threadIdx.x >= off) ? tmp[threadIdx.x - off] : 0;
        __syncthreads();
        tmp[threadIdx.x] += t;
        __syncthreads();
    }
    if (i < N) excl[i] = tmp[threadIdx.x] - v;
    if (threadIdx.x == 255) bsum[blockIdx.x] = tmp[255];
}

__global__ __launch_bounds__(256) void scan2_kernel(int* __restrict__ bsum, int nb) {
    __shared__ int tmp[256];
    int i = threadIdx.x;
    int v = (i < nb) ? bsum[i] : 0;
    tmp[i] = v;
    __syncthreads();
    for (int off = 1; off < 256; off <<= 1) {
        int t = (i >= off) ? tmp[i - off] : 0;
        __syncthreads();
        tmp[i] += t;
        __syncthreads();
    }
    if (i < nb) bsum[i] = tmp[i] - v;  // exclusive block offsets, in place
}

__global__ void scan3_kernel(const int* __restrict__ excl,
                             const int* __restrict__ bsum,
                             int* __restrict__ rowptr, int N, int E) {
    int i = blockIdx.x * 256 + threadIdx.x;
    if (i < N) rowptr[i] = excl[i] + bsum[blockIdx.x];
    if (i == 0) rowptr[N] = E;
}

// csr[rowptr[dst]+seq[e]] = (src, ew-bits) — no atomics, plain writes
__global__ __launch_bounds__(256) void scatter_csr_kernel(
    const void* __restrict__ ei, const float* __restrict__ ew,
    const int* __restrict__ flag, const int* __restrict__ rowptr,
    const int* __restrict__ seq, int2* __restrict__ csr, int E) {
    int is64 = *flag;
    int T = gridDim.x * 256;
    int i = blockIdx.x * 256 + threadIdx.x;
#pragma unroll
    for (int u = 0; u < 2; ++u) {
        int e = i + u * T;
        if (e < E) {
            int src = edge_idx(ei, is64, e);
            int dst = edge_idx(ei, is64, (long long)E + e);
            int pos = rowptr[dst] + seq[e];
            csr[pos] = make_int2(src, __float_as_int(ew[e]));
        }
    }
}

// deg[n] = 1 + sum ew over row; dinv = rsqrt, invdeg = 1/deg
__global__ void deg_inv_kernel(const int* __restrict__ rowptr,
                               const int2* __restrict__ csr,
                               float* __restrict__ dinv,
                               float* __restrict__ invdeg, int N) {
    int n = blockIdx.x * 256 + threadIdx.x;
    if (n < N) {
        int b = rowptr[n], e = rowptr[n + 1];
        float d = 1.0f;
        for (int k = b; k < e; ++k) d += __int_as_float(csr[k].y);
        dinv[n]   = rsqrtf(d);
        invdeg[n] = 1.0f / d;
    }
}

// csr[k].y: ew -> norm = dinv[src]*ew*dinv[n]
__global__ void norm_kernel(const int* __restrict__ rowptr,
                            const float* __restrict__ dinv,
                            int2* __restrict__ csr, int N) {
    int n = blockIdx.x * 256 + threadIdx.x;
    if (n < N) {
        int b = rowptr[n], e = rowptr[n + 1];
        float dn = dinv[n];
        for (int k = b; k < e; ++k) {
            int2 ed = csr[k];
            csr[k].y = __float_as_int(dinv[ed.x] * __int_as_float(ed.y) * dn);
        }
    }
}

// ---------------------------------------------------------------------------
// out[i][c] = sum_k in'[i][k] * W[k][c],  in' = affine? relu(in*a+s) : in
// 64 rows/block; thread = (rowgroup rg of 4 rows, colquad q of 4 cols).
// ---------------------------------------------------------------------------
__global__ __launch_bounds__(256) void gemm64_kernel(
    const float* __restrict__ in, const float* __restrict__ W,
    const float* __restrict__ scale, const float* __restrict__ shift,
    float* __restrict__ out, int N, int affine) {
    __shared__ float4 Ws4[64][16];      // W[k][c] as float4 over c
    __shared__ float xs[64][65];        // padded: breaks bank conflicts
    __shared__ float sA[64], sS[64];
    int tid = threadIdx.x;
    const float4* W4 = (const float4*)W;
    for (int j = tid; j < 1024; j += 256) Ws4[j >> 4][j & 15] = W4[j];
    if (affine && tid < 64) { sA[tid] = scale[tid]; sS[tid] = shift[tid]; }
    __syncthreads();

    int rowBase = blockIdx.x * 64;
    // stage 64 rows of input (affine+relu applied on load for layer 2)
    for (int j = tid; j < 1024; j += 256) {
        int r = j >> 4, q = j & 15;
        int row = rowBase + r;
        float4 v = make_float4(0.f, 0.f, 0.f, 0.f);
        if (row < N) {
            v = ((const float4*)in)[(size_t)row * 16 + q];
            if (affine) {
                int c = q * 4;
                v.x = fmaxf(fmaf(v.x, sA[c + 0], sS[c + 0]), 0.f);
                v.y = fmaxf(fmaf(v.y, sA[c + 1], sS[c + 1]), 0.f);
                v.z = fmaxf(fmaf(v.z, sA[c + 2], sS[c + 2]), 0.f);
                v.w = fmaxf(fmaf(v.w, sA[c + 3], sS[c + 3]), 0.f);
            }
        }
        xs[r][q * 4 + 0] = v.x;
        xs[r][q * 4 + 1] = v.y;
        xs[r][q * 4 + 2] = v.z;
        xs[r][q * 4 + 3] = v.w;
    }
    __syncthreads();

    int q = tid & 15, rg = tid >> 4;    // 16 rowgroups x 16 colquads
    int r0 = rg * 4;
    float4 a0 = make_float4(0.f, 0.f, 0.f, 0.f), a1 = a0, a2 = a0, a3 = a0;
#pragma unroll 4
    for (int k = 0; k < 64; ++k) {
        float4 wv = Ws4[k][q];
        a0 = f4fma(xs[r0 + 0][k], wv, a0);
        a1 = f4fma(xs[r0 + 1][k], wv, a1);
        a2 = f4fma(xs[r0 + 2][k], wv, a2);
        a3 = f4fma(xs[r0 + 3][k], wv, a3);
    }
    int row = rowBase + r0;
    float4* o4 = (float4*)out;
    if (row + 0 < N) o4[(size_t)(row + 0) * 16 + q] = a0;
    if (row + 1 < N) o4[(size_t)(row + 1) * 16 + q] = a1;
    if (row + 2 < N) o4[(size_t)(row + 2) * 16 + q] = a2;
    if (row + 3 < N) o4[(size_t)(row + 3) * 16 + q] = a3;
}

// ---------------------------------------------------------------------------
// agg[n][c] = h[n][c]*invdeg[n] + bias[c] + sum_k norm[k]*h[src[k]][c]
// One wave per node; 4 subgroups of 16 lanes each own every-4th edge,
// each edge row gathered as 16 x float4; unroll 2 -> 8 edges in flight.
// ---------------------------------------------------------------------------
__global__ __launch_bounds__(256) void gather_agg_kernel(
    const float* __restrict__ h, const int* __restrict__ rowptr,
    const int2* __restrict__ csr, const float* __restrict__ invdeg,
    const float* __restrict__ bias, float* __restrict__ agg, int N) {
    int tid = threadIdx.x;
    int wave = tid >> 6, lane = tid & 63;
    int sub = lane >> 4, sl = lane & 15;
    int n = blockIdx.x * 4 + wave;
    if (n >= N) return;
    const float4* h4 = (const float4*)h;
    int beg = rowptr[n], end = rowptr[n + 1];

    float4 acc;
    if (sub == 0) {
        float4 hv = h4[(size_t)n * 16 + sl];
        float4 bv = ((const float4*)bias)[sl];
        float id = invdeg[n];
        acc = f4fma(id, hv, bv);
    } else {
        acc = make_float4(0.f, 0.f, 0.f, 0.f);
    }

    int k = beg + sub;
    for (; k + 4 < end; k += 8) {
        int2 e0 = csr[k];
        int2 e1 = csr[k + 4];
        float4 h0 = h4[(size_t)e0.x * 16 + sl];
        float4 h1 = h4[(size_t)e1.x * 16 + sl];
        acc = f4fma(__int_as_float(e0.y), h0, acc);
        acc = f4fma(__int_as_float(e1.y), h1, acc);
    }
    if (k < end) {
        int2 e0 = csr[k];
        float4 h0 = h4[(size_t)e0.x * 16 + sl];
        acc = f4fma(__int_as_float(e0.y), h0, acc);
    }

    // combine the 4 subgroup partials (xor over lane bits 4,5)
    acc.x += __shfl_xor(acc.x, 16); acc.y += __shfl_xor(acc.y, 16);
    acc.z += __shfl_xor(acc.z, 16); acc.w += __shfl_xor(acc.w, 16);
    acc.x += __shfl_xor(acc.x, 32); acc.y += __shfl_xor(acc.y, 32);
    acc.z += __shfl_xor(acc.z, 32); acc.w += __shfl_xor(acc.w, 32);

    if (sub == 0) ((float4*)agg)[(size_t)n * 16 + sl] = acc;
}

// per-feature sum / sumsq over rows (float4; thread = (rowgroup, colquad))
__global__ __launch_bounds__(256) void bn_stats_kernel(
    const float* __restrict__ h, float* __restrict__ sum,
    float* __restrict__ sumsq, int N) {
    int tid = threadIdx.x;
    int q = tid & 15, rg = tid >> 4;
    const float4* h4 = (const float4*)h;
    float4 s = make_float4(0.f, 0.f, 0.f, 0.f), sq = s;
    for (int row = blockIdx.x * 16 + rg; row < N; row += gridDim.x * 16) {
        float4 v = h4[(size_t)row * 16 + q];
        s.x += v.x; s.y += v.y; s.z += v.z; s.w += v.w;
        sq.x = fmaf(v.x, v.x, sq.x); sq.y = fmaf(v.y, v.y, sq.y);
        sq.z = fmaf(v.z, v.z, sq.z); sq.w = fmaf(v.w, v.w, sq.w);
    }
    __shared__ float4 sS[16][16], sQ[16][16];
    sS[rg][q] = s; sQ[rg][q] = sq;
    __syncthreads();
    if (tid < 16) {
        float4 ts = sS[0][tid], tq = sQ[0][tid];
        for (int i = 1; i < 16; ++i) {
            float4 a = sS[i][tid], b = sQ[i][tid];
            ts.x += a.x; ts.y += a.y; ts.z += a.z; ts.w += a.w;
            tq.x += b.x; tq.y += b.y; tq.z += b.z; tq.w += b.w;
        }
        int c = tid * 4;
        unsafeAtomicAdd(&sum[c + 0], ts.x);   unsafeAtomicAdd(&sum[c + 1], ts.y);
        unsafeAtomicAdd(&sum[c + 2], ts.z);   unsafeAtomicAdd(&sum[c + 3], ts.w);
        unsafeAtomicAdd(&sumsq[c + 0], tq.x); unsafeAtomicAdd(&sumsq[c + 1], tq.y);
        unsafeAtomicAdd(&sumsq[c + 2], tq.z); unsafeAtomicAdd(&sumsq[c + 3], tq.w);
    }
}

// a[c] = gamma*rsqrt(var+eps); s[c] = beta - mean*a
__global__ void bn_final_kernel(const float* __restrict__ sum,
                                const float* __restrict__ sumsq,
                                const float* __restrict__ gamma,
                                const float* __restrict__ beta,
                                float* __restrict__ a, float* __restrict__ s,
                                float invN) {
    int c = threadIdx.x;
    if (c < 64) {
        float m = sum[c] * invN;
        float var = fmaxf(sumsq[c] * invN - m * m, 0.0f);
        float aa = gamma[c] * rsqrtf(var + BN_EPS);
        a[c] = aa;
        s[c] = beta[c] - m * aa;
    }
}

// out = relu(agg*a + s + x), float4
__global__ void final_out_kernel(const float* __restrict__ agg,
                                 const float* __restrict__ a,
                                 const float* __restrict__ s,
                                 const float* __restrict__ x,
                                 float* __restrict__ out, int nquads) {
    int gid = blockIdx.x * 256 + threadIdx.x;
    if (gid < nquads) {
        int q = gid & 15;
        float4 av = ((const float4*)a)[q], sv = ((const float4*)s)[q];
        float4 g = ((const float4*)agg)[gid], xv = ((const float4*)x)[gid];
        float4 o;
        o.x = fmaxf(fmaf(g.x, av.x, sv.x) + xv.x, 0.f);
        o.y = fmaxf(fmaf(g.y, av.y, sv.y) + xv.y, 0.f);
        o.z = fmaxf(fmaf(g.z, av.z, sv.z) + xv.z, 0.f);
        o.w = fmaxf(fmaf(g.w, av.w, sv.w) + xv.w, 0.f);
        ((float4*)out)[gid] = o;
    }
}

extern "C" void kernel_launch(void* const* d_in, const int* in_sizes, int n_in,
                              void* d_out, int out_size, void* d_ws, size_t ws_size,
                              hipStream_t stream) {
    const float* x      = (const float*)d_in[0];
    const void*  ei     = d_in[1];           // int64 or int32, detected on device
    const float* ew     = (const float*)d_in[2];
    const float* W1     = (const float*)d_in[3];
    const float* b1     = (const float*)d_in[4];
    const float* gamma1 = (const float*)d_in[5];
    const float* beta1  = (const float*)d_in[6];
    const float* W2     = (const float*)d_in[7];
    const float* b2     = (const float*)d_in[8];
    const float* gamma2 = (const float*)d_in[9];
    const float* beta2  = (const float*)d_in[10];
    float* out = (float*)d_out;

    const int N = in_sizes[0] / FEAT;
    const int E = in_sizes[2];

    // workspace layout (256B-aligned chunks)
    char* ws = (char*)d_ws;
    size_t off = 0;
    auto alloc = [&](size_t bytes) {
        size_t o = off;
        off += (bytes + 255) & ~(size_t)255;
        return (void*)(ws + o);
    };
    int*   flag   = (int*)  alloc(256);
    int*   cnt    = (int*)  alloc((size_t)N * 4);
    int*   rowptr = (int*)  alloc((size_t)(N + 1) * 4);
    int*   seq    = (int*)  alloc((size_t)E * 4);
    int*   excl   = (int*)  alloc((size_t)N * 4);
    int*   bsum   = (int*)  alloc(256 * 4);
    float* dinv   = (float*)alloc((size_t)N * 4);
    float* invdeg = (float*)alloc((size_t)N * 4);
    float* sums   = (float*)alloc(256 * 4);   // sum1[64] sq1[64] sum2[64] sq2[64]
    float* ab     = (float*)alloc(256 * 4);   // a1[64] s1[64] a2[64] s2[64]
    int2*  csr    = (int2*) alloc((size_t)E * 8);
    float* h      = (float*)alloc((size_t)N * FEAT * 4);
    float* agg    = (float*)alloc((size_t)N * FEAT * 4);

    const int nblkN  = (N + 255) / 256;
    const int nblkE8 = (E + 2047) / 2048;
    const int nblkE2 = (E + 511) / 512;
    const int nblkQ  = (N * 16 + 255) / 256;
    const int nblkG  = (N + 63) / 64;
    const int nblkA  = (N + 3) / 4;

    // ---- CSR build (shared by both layers; 800K atomics total) ----
    init_kernel<<<nblkN, 256, 0, stream>>>((const unsigned*)ei, flag, cnt, sums, N);
    count_seq_kernel<<<nblkE8, 256, 0, stream>>>(ei, flag, cnt, seq, E);
    scan1_kernel<<<nblkN, 256, 0, stream>>>(cnt, excl, bsum, N);
    scan2_kernel<<<1, 256, 0, stream>>>(bsum, nblkN);
    scan3_kernel<<<nblkN, 256, 0, stream>>>(excl, bsum, rowptr, N, E);
    scatter_csr_kernel<<<nblkE2, 256, 0, stream>>>(ei, ew, flag, rowptr, seq, csr, E);
    deg_inv_kernel<<<nblkN, 256, 0, stream>>>(rowptr, csr, dinv, invdeg, N);
    norm_kernel<<<nblkN, 256, 0, stream>>>(rowptr, dinv, csr, N);

    // ---- layer 1 ----
    gemm64_kernel<<<nblkG, 256, 0, stream>>>(x, W1, nullptr, nullptr, h, N, 0);
    gather_agg_kernel<<<nblkA, 256, 0, stream>>>(h, rowptr, csr, invdeg, b1, agg, N);
    bn_stats_kernel<<<256, 256, 0, stream>>>(agg, sums, sums + 64, N);
    bn_final_kernel<<<1, 64, 0, stream>>>(sums, sums + 64, gamma1, beta1,
                                          ab, ab + 64, 1.0f / (float)N);

    // ---- layer 2 (gemm fuses BN1 apply + relu on input load) ----
    gemm64_kernel<<<nblkG, 256, 0, stream>>>(agg, W2, ab, ab + 64, h, N, 1);
    gather_agg_kernel<<<nblkA, 256, 0, stream>>>(h, rowptr, csr, invdeg, b2, agg, N);
    bn_stats_kernel<<<256, 256, 0, stream>>>(agg, sums + 128, sums + 192, N);
    bn_final_kernel<<<1, 64, 0, stream>>>(sums + 128, sums + 192, gamma2, beta2,
                                          ab + 128, ab + 192, 1.0f / (float)N);

    // ---- residual + relu ----
    final_out_kernel<<<nblkQ, 256, 0, stream>>>(agg, ab + 128, ab + 192, x,
                                                out, N * 16);
}

// Round 5
// 218.227 us; speedup vs baseline: 7.0239x; 1.1096x over previous
//
#include <hip/hip_runtime.h>
#include <math.h>

#define FEAT 64
#define BN_EPS 1e-5f

__device__ __forceinline__ int edge_idx(const void* p, int is64, long long i) {
    return is64 ? (int)((const long long*)p)[i] : ((const int*)p)[i];
}

__device__ __forceinline__ float4 f4fma(float a, float4 b, float4 c) {
    return make_float4(fmaf(a, b.x, c.x), fmaf(a, b.y, c.y),
                       fmaf(a, b.z, c.z), fmaf(a, b.w, c.w));
}

// bf16 pack (round-to-nearest-even) / unpack-as-bit-ops
__device__ __forceinline__ unsigned bf16rtne(float f) {
    unsigned u = __float_as_uint(f);
    return (u + 0x7fffu + ((u >> 16) & 1u)) >> 16;
}
__device__ __forceinline__ unsigned packbf2(float a, float b) {
    return bf16rtne(a) | (bf16rtne(b) << 16);
}
__device__ __forceinline__ float4 unpackbf4(uint2 r) {
    return make_float4(__uint_as_float(r.x << 16),
                       __uint_as_float(r.x & 0xffff0000u),
                       __uint_as_float(r.y << 16),
                       __uint_as_float(r.y & 0xffff0000u));
}

// ---------------------------------------------------------------------------
// init: cnt[i]=0; first 8 blocks zero the BN partial buckets (2 layers x 8
// replicas x 128); block 0 detects edge_index dtype (int64 high words all 0).
// ---------------------------------------------------------------------------
__global__ __launch_bounds__(256) void init_kernel(
    const unsigned* __restrict__ w, int* __restrict__ flag,
    int* __restrict__ cnt, float* __restrict__ parts, int N) {
    int i = blockIdx.x * 256 + threadIdx.x;
    if (i < N) cnt[i] = 0;
    if (blockIdx.x < 8) parts[blockIdx.x * 256 + threadIdx.x] = 0.0f;
    if (blockIdx.x == 0 && threadIdx.x < 64) {
        unsigned long long ok = __ballot(w[2 * threadIdx.x + 1] == 0u);
        if (threadIdx.x == 0) *flag = (ok == ~0ull);
    }
}

// count edges per dst; seq[e] = arrival slot within its dst row (the atomic's
// return value). 8 independent atomics in flight per thread.
__global__ __launch_bounds__(256) void count_seq_kernel(
    const void* __restrict__ ei, const int* __restrict__ flag,
    int* __restrict__ cnt, int* __restrict__ seq, int E) {
    int is64 = *flag;
    int T = gridDim.x * 256;
    int i = blockIdx.x * 256 + threadIdx.x;
#pragma unroll
    for (int u = 0; u < 8; ++u) {
        int e = i + u * T;
        if (e < E) {
            int dst = edge_idx(ei, is64, (long long)E + e);
            seq[e] = atomicAdd(&cnt[dst], 1);
        }
    }
}

// ---- exclusive scan over cnt[N] -> rowptr (3-level; N <= 256*256) ----------
__global__ __launch_bounds__(256) void scan1_kernel(const int* __restrict__ cnt,
                                                    int* __restrict__ excl,
                                                    int* __restrict__ bsum, int N) {
    __shared__ int tmp[256];
    int i = blockIdx.x * 256 + threadIdx.x;
    int v = (i < N) ? cnt[i] : 0;
    tmp[threadIdx.x] = v;
    __syncthreads();
    for (int off = 1; off < 256; off <<= 1) {
        int t = (threadIdx.x >= off) ? tmp[threadIdx.x - off] : 0;
        __syncthreads();
        tmp[threadIdx.x] += t;
        __syncthreads();
    }
    if (i < N) excl[i] = tmp[threadIdx.x] - v;
    if (threadIdx.x == 255) bsum[blockIdx.x] = tmp[255];
}

__global__ __launch_bounds__(256) void scan2_kernel(int* __restrict__ bsum, int nb) {
    __shared__ int tmp[256];
    int i = threadIdx.x;
    int v = (i < nb) ? bsum[i] : 0;
    tmp[i] = v;
    __syncthreads();
    for (int off = 1; off < 256; off <<= 1) {
        int t = (i >= off) ? tmp[i - off] : 0;
        __syncthreads();
        tmp[i] += t;
        __syncthreads();
    }
    if (i < nb) bsum[i] = tmp[i] - v;  // exclusive block offsets, in place
}

__global__ void scan3_kernel(const int* __restrict__ excl,
                             const int* __restrict__ bsum,
                             int* __restrict__ rowptr, int N, int E) {
    int i = blockIdx.x * 256 + threadIdx.x;
    if (i < N) rowptr[i] = excl[i] + bsum[blockIdx.x];
    if (i == 0) rowptr[N] = E;
}

// csr[rowptr[dst]+seq[e]] = (src, ew-bits) — no atomics, plain writes
__global__ __launch_bounds__(256) void scatter_csr_kernel(
    const void* __restrict__ ei, const float* __restrict__ ew,
    const int* __restrict__ flag, const int* __restrict__ rowptr,
    const int* __restrict__ seq, int2* __restrict__ csr, int E) {
    int is64 = *flag;
    int T = gridDim.x * 256;
    int i = blockIdx.x * 256 + threadIdx.x;
#pragma unroll
    for (int u = 0; u < 2; ++u) {
        int e = i + u * T;
        if (e < E) {
            int src = edge_idx(ei, is64, e);
            int dst = edge_idx(ei, is64, (long long)E + e);
            int pos = rowptr[dst] + seq[e];
            csr[pos] = make_int2(src, __float_as_int(ew[e]));
        }
    }
}

// deg[n] = 1 + sum ew over row; 8 lanes per node, shfl reduce
__global__ __launch_bounds__(256) void deg_inv_kernel(
    const int* __restrict__ rowptr, const int2* __restrict__ csr,
    float* __restrict__ dinv, float* __restrict__ invdeg, int N) {
    int t = blockIdx.x * 256 + threadIdx.x;
    int n = t >> 3, l = t & 7;
    if (n >= N) return;
    int b = rowptr[n], e = rowptr[n + 1];
    float d = 0.0f;
    for (int k = b + l; k < e; k += 8) d += __int_as_float(csr[k].y);
    d += __shfl_xor(d, 1);
    d += __shfl_xor(d, 2);
    d += __shfl_xor(d, 4);
    if (l == 0) {
        d += 1.0f;
        dinv[n]   = rsqrtf(d);
        invdeg[n] = 1.0f / d;
    }
}

// edge-parallel, coalesced fold: csr[k].y = ew -> dinv[src]*ew
// (dinv[dst] is applied once per node in the gather epilogue)
__global__ __launch_bounds__(256) void fold_kernel(int2* __restrict__ csr,
                                                   const float* __restrict__ dinv,
                                                   int E) {
    int T = gridDim.x * 256;
    int i = blockIdx.x * 256 + threadIdx.x;
#pragma unroll
    for (int u = 0; u < 2; ++u) {
        int e = i + u * T;
        if (e < E) {
            int2 v = csr[e];
            csr[e].y = __float_as_int(dinv[v.x] * __int_as_float(v.y));
        }
    }
}

// ---------------------------------------------------------------------------
// out_bf[i][c] = bf16( sum_k in'[i][k] * W[k][c] ), in' = affine? relu : id
// 64 rows/block; thread = (rowgroup rg of 4 rows, colquad q of 4 cols).
// ---------------------------------------------------------------------------
__global__ __launch_bounds__(256) void gemm64_kernel(
    const float* __restrict__ in, const float* __restrict__ W,
    const float* __restrict__ scale, const float* __restrict__ shift,
    uint2* __restrict__ out_bf, int N, int affine) {
    __shared__ float4 Ws4[64][16];      // W[k][c] as float4 over c
    __shared__ float xs[64][65];        // padded: breaks bank conflicts
    __shared__ float sA[64], sS[64];
    int tid = threadIdx.x;
    const float4* W4 = (const float4*)W;
    for (int j = tid; j < 1024; j += 256) Ws4[j >> 4][j & 15] = W4[j];
    if (affine && tid < 64) { sA[tid] = scale[tid]; sS[tid] = shift[tid]; }
    __syncthreads();

    int rowBase = blockIdx.x * 64;
    for (int j = tid; j < 1024; j += 256) {
        int r = j >> 4, q = j & 15;
        int row = rowBase + r;
        float4 v = make_float4(0.f, 0.f, 0.f, 0.f);
        if (row < N) {
            v = ((const float4*)in)[(size_t)row * 16 + q];
            if (affine) {
                int c = q * 4;
                v.x = fmaxf(fmaf(v.x, sA[c + 0], sS[c + 0]), 0.f);
                v.y = fmaxf(fmaf(v.y, sA[c + 1], sS[c + 1]), 0.f);
                v.z = fmaxf(fmaf(v.z, sA[c + 2], sS[c + 2]), 0.f);
                v.w = fmaxf(fmaf(v.w, sA[c + 3], sS[c + 3]), 0.f);
            }
        }
        xs[r][q * 4 + 0] = v.x;
        xs[r][q * 4 + 1] = v.y;
        xs[r][q * 4 + 2] = v.z;
        xs[r][q * 4 + 3] = v.w;
    }
    __syncthreads();

    int q = tid & 15, rg = tid >> 4;
    int r0 = rg * 4;
    float4 a0 = make_float4(0.f, 0.f, 0.f, 0.f), a1 = a0, a2 = a0, a3 = a0;
#pragma unroll 4
    for (int k = 0; k < 64; ++k) {
        float4 wv = Ws4[k][q];
        a0 = f4fma(xs[r0 + 0][k], wv, a0);
        a1 = f4fma(xs[r0 + 1][k], wv, a1);
        a2 = f4fma(xs[r0 + 2][k], wv, a2);
        a3 = f4fma(xs[r0 + 3][k], wv, a3);
    }
    int row = rowBase + r0;
    if (row + 0 < N) out_bf[(size_t)(row + 0) * 16 + q] = make_uint2(packbf2(a0.x, a0.y), packbf2(a0.z, a0.w));
    if (row + 1 < N) out_bf[(size_t)(row + 1) * 16 + q] = make_uint2(packbf2(a1.x, a1.y), packbf2(a1.z, a1.w));
    if (row + 2 < N) out_bf[(size_t)(row + 2) * 16 + q] = make_uint2(packbf2(a2.x, a2.y), packbf2(a2.z, a2.w));
    if (row + 3 < N) out_bf[(size_t)(row + 3) * 16 + q] = make_uint2(packbf2(a3.x, a3.y), packbf2(a3.z, a3.w));
}

// ---------------------------------------------------------------------------
// agg[n] = dinv[n]*sum_k w'[k]*h[src[k]] + invdeg[n]*h[n] + bias   (w'=dinv*ew)
// + fused BN column stats (sum, sumsq) -> 8-replica atomic buckets.
// Persistent grid (2048 blocks), wave per node, 4x16-lane subgroups,
// h rows in bf16 (uint2 = 4 bf16 per lane).
// ---------------------------------------------------------------------------
__global__ __launch_bounds__(256) void gather_agg_kernel(
    const uint2* __restrict__ h2, const int* __restrict__ rowptr,
    const int2* __restrict__ csr, const float* __restrict__ dinv,
    const float* __restrict__ invdeg, const float* __restrict__ bias,
    float* __restrict__ agg, float* __restrict__ parts, int N) {
    int tid = threadIdx.x;
    int wave = tid >> 6, lane = tid & 63;
    int sub = lane >> 4, sl = lane & 15;
    float4 bv = ((const float4*)bias)[sl];
    float4 bnS = make_float4(0.f, 0.f, 0.f, 0.f), bnQ = bnS;

    for (int n = blockIdx.x * 4 + wave; n < N; n += gridDim.x * 4) {
        int beg = rowptr[n], end = rowptr[n + 1];
        float4 accE = make_float4(0.f, 0.f, 0.f, 0.f);
        int k = beg + sub;
        for (; k + 4 < end; k += 8) {
            int2 e0 = csr[k];
            int2 e1 = csr[k + 4];
            float4 h0 = unpackbf4(h2[(size_t)e0.x * 16 + sl]);
            float4 h1 = unpackbf4(h2[(size_t)e1.x * 16 + sl]);
            accE = f4fma(__int_as_float(e0.y), h0, accE);
            accE = f4fma(__int_as_float(e1.y), h1, accE);
        }
        if (k < end) {
            int2 e0 = csr[k];
            float4 h0 = unpackbf4(h2[(size_t)e0.x * 16 + sl]);
            accE = f4fma(__int_as_float(e0.y), h0, accE);
        }
        // combine the 4 subgroup partials (xor over lane bits 4,5)
        accE.x += __shfl_xor(accE.x, 16); accE.y += __shfl_xor(accE.y, 16);
        accE.z += __shfl_xor(accE.z, 16); accE.w += __shfl_xor(accE.w, 16);
        accE.x += __shfl_xor(accE.x, 32); accE.y += __shfl_xor(accE.y, 32);
        accE.z += __shfl_xor(accE.z, 32); accE.w += __shfl_xor(accE.w, 32);

        if (sub == 0) {
            float4 self = unpackbf4(h2[(size_t)n * 16 + sl]);
            float4 tot = f4fma(invdeg[n], self, bv);
            tot = f4fma(dinv[n], accE, tot);
            ((float4*)agg)[(size_t)n * 16 + sl] = tot;
            bnS.x += tot.x; bnS.y += tot.y; bnS.z += tot.z; bnS.w += tot.w;
            bnQ.x = fmaf(tot.x, tot.x, bnQ.x); bnQ.y = fmaf(tot.y, tot.y, bnQ.y);
            bnQ.z = fmaf(tot.z, tot.z, bnQ.z); bnQ.w = fmaf(tot.w, tot.w, bnQ.w);
        }
    }

    __shared__ float4 LS[4][16], LQ[4][16];
    if (sub == 0) { LS[wave][sl] = bnS; LQ[wave][sl] = bnQ; }
    __syncthreads();
    if (tid < 16) {
        float4 ts = LS[0][tid], tq = LQ[0][tid];
        for (int i = 1; i < 4; ++i) {
            float4 a = LS[i][tid], b = LQ[i][tid];
            ts.x += a.x; ts.y += a.y; ts.z += a.z; ts.w += a.w;
            tq.x += b.x; tq.y += b.y; tq.z += b.z; tq.w += b.w;
        }
        // replica bucket: [rep][ sum[64] | sq[64] ]
        float* P = parts + (size_t)(blockIdx.x & 7) * 128;
        int c = tid * 4;
        unsafeAtomicAdd(&P[c + 0], ts.x);      unsafeAtomicAdd(&P[c + 1], ts.y);
        unsafeAtomicAdd(&P[c + 2], ts.z);      unsafeAtomicAdd(&P[c + 3], ts.w);
        unsafeAtomicAdd(&P[64 + c + 0], tq.x); unsafeAtomicAdd(&P[64 + c + 1], tq.y);
        unsafeAtomicAdd(&P[64 + c + 2], tq.z); unsafeAtomicAdd(&P[64 + c + 3], tq.w);
    }
}

// reduce 8 replicas; a[c] = gamma*rsqrt(var+eps); s[c] = beta - mean*a
__global__ void bn_final_kernel(const float* __restrict__ parts,
                                const float* __restrict__ gamma,
                                const float* __restrict__ beta,
                                float* __restrict__ a, float* __restrict__ s,
                                float invN) {
    int c = threadIdx.x;
    if (c < 64) {
        float sm = 0.f, sq = 0.f;
#pragma unroll
        for (int r = 0; r < 8; ++r) {
            sm += parts[r * 128 + c];
            sq += parts[r * 128 + 64 + c];
        }
        float m = sm * invN;
        float var = fmaxf(sq * invN - m * m, 0.0f);
        float aa = gamma[c] * rsqrtf(var + BN_EPS);
        a[c] = aa;
        s[c] = beta[c] - m * aa;
    }
}

// out = relu(agg*a + s + x), float4
__global__ void final_out_kernel(const float* __restrict__ agg,
                                 const float* __restrict__ a,
                                 const float* __restrict__ s,
                                 const float* __restrict__ x,
                                 float* __restrict__ out, int nquads) {
    int gid = blockIdx.x * 256 + threadIdx.x;
    if (gid < nquads) {
        int q = gid & 15;
        float4 av = ((const float4*)a)[q], sv = ((const float4*)s)[q];
        float4 g = ((const float4*)agg)[gid], xv = ((const float4*)x)[gid];
        float4 o;
        o.x = fmaxf(fmaf(g.x, av.x, sv.x) + xv.x, 0.f);
        o.y = fmaxf(fmaf(g.y, av.y, sv.y) + xv.y, 0.f);
        o.z = fmaxf(fmaf(g.z, av.z, sv.z) + xv.z, 0.f);
        o.w = fmaxf(fmaf(g.w, av.w, sv.w) + xv.w, 0.f);
        ((float4*)out)[gid] = o;
    }
}

extern "C" void kernel_launch(void* const* d_in, const int* in_sizes, int n_in,
                              void* d_out, int out_size, void* d_ws, size_t ws_size,
                              hipStream_t stream) {
    const float* x      = (const float*)d_in[0];
    const void*  ei     = d_in[1];           // int64 or int32, detected on device
    const float* ew     = (const float*)d_in[2];
    const float* W1     = (const float*)d_in[3];
    const float* b1     = (const float*)d_in[4];
    const float* gamma1 = (const float*)d_in[5];
    const float* beta1  = (const float*)d_in[6];
    const float* W2     = (const float*)d_in[7];
    const float* b2     = (const float*)d_in[8];
    const float* gamma2 = (const float*)d_in[9];
    const float* beta2  = (const float*)d_in[10];
    float* out = (float*)d_out;

    const int N = in_sizes[0] / FEAT;
    const int E = in_sizes[2];

    // workspace layout (256B-aligned chunks)
    char* ws = (char*)d_ws;
    size_t off = 0;
    auto alloc = [&](size_t bytes) {
        size_t o = off;
        off += (bytes + 255) & ~(size_t)255;
        return (void*)(ws + o);
    };
    int*   flag   = (int*)  alloc(256);
    int*   cnt    = (int*)  alloc((size_t)N * 4);
    int*   rowptr = (int*)  alloc((size_t)(N + 1) * 4);
    int*   seq    = (int*)  alloc((size_t)E * 4);
    int*   excl   = (int*)  alloc((size_t)N * 4);
    int*   bsum   = (int*)  alloc(256 * 4);
    float* dinv   = (float*)alloc((size_t)N * 4);
    float* invdeg = (float*)alloc((size_t)N * 4);
    float* parts  = (float*)alloc(2 * 8 * 128 * 4);  // 2 layers x 8 reps x 128
    float* ab     = (float*)alloc(256 * 4);          // a1 s1 a2 s2
    int2*  csr    = (int2*) alloc((size_t)E * 8);
    uint2* h_bf   = (uint2*)alloc((size_t)N * 16 * 8);  // N x 64 bf16
    float* agg    = (float*)alloc((size_t)N * FEAT * 4);

    const int nblkN  = (N + 255) / 256;
    const int nblkN8 = (N * 8 + 255) / 256;
    const int nblkE8 = (E + 2047) / 2048;
    const int nblkE2 = (E + 511) / 512;
    const int nblkQ  = (N * 16 + 255) / 256;
    const int nblkG  = (N + 63) / 64;
    const int GATHER_BLKS = 2048;   // 8 blocks/CU, grid-stride over nodes

    // ---- CSR build (shared by both layers) ----
    init_kernel<<<nblkN, 256, 0, stream>>>((const unsigned*)ei, flag, cnt, parts, N);
    count_seq_kernel<<<nblkE8, 256, 0, stream>>>(ei, flag, cnt, seq, E);
    scan1_kernel<<<nblkN, 256, 0, stream>>>(cnt, excl, bsum, N);
    scan2_kernel<<<1, 256, 0, stream>>>(bsum, nblkN);
    scan3_kernel<<<nblkN, 256, 0, stream>>>(excl, bsum, rowptr, N, E);
    scatter_csr_kernel<<<nblkE2, 256, 0, stream>>>(ei, ew, flag, rowptr, seq, csr, E);
    deg_inv_kernel<<<nblkN8, 256, 0, stream>>>(rowptr, csr, dinv, invdeg, N);
    fold_kernel<<<nblkE2, 256, 0, stream>>>(csr, dinv, E);

    // ---- layer 1 ----
    gemm64_kernel<<<nblkG, 256, 0, stream>>>(x, W1, nullptr, nullptr, h_bf, N, 0);
    gather_agg_kernel<<<GATHER_BLKS, 256, 0, stream>>>(h_bf, rowptr, csr, dinv,
                                                       invdeg, b1, agg, parts, N);
    bn_final_kernel<<<1, 64, 0, stream>>>(parts, gamma1, beta1,
                                          ab, ab + 64, 1.0f / (float)N);

    // ---- layer 2 (gemm fuses BN1 apply + relu on input load) ----
    gemm64_kernel<<<nblkG, 256, 0, stream>>>(agg, W2, ab, ab + 64, h_bf, N, 1);
    gather_agg_kernel<<<GATHER_BLKS, 256, 0, stream>>>(h_bf, rowptr, csr, dinv,
                                                       invdeg, b2, agg, parts + 1024, N);
    bn_final_kernel<<<1, 64, 0, stream>>>(parts + 1024, gamma2, beta2,
                                          ab + 128, ab + 192, 1.0f / (float)N);

    // ---- residual + relu ----
    final_out_kernel<<<nblkQ, 256, 0, stream>>>(agg, ab + 128, ab + 192, x,
                                                out, N * 16);
}

// Round 7
// 208.627 us; speedup vs baseline: 7.3471x; 1.0460x over previous
//
#include <hip/hip_runtime.h>
#include <math.h>

#define FEAT 64
#define BN_EPS 1e-5f
#define BN_REPS 64

__device__ __forceinline__ int edge_idx(const void* p, int is64, long long i) {
    return is64 ? (int)((const long long*)p)[i] : ((const int*)p)[i];
}

__device__ __forceinline__ float4 f4fma(float a, float4 b, float4 c) {
    return make_float4(fmaf(a, b.x, c.x), fmaf(a, b.y, c.y),
                       fmaf(a, b.z, c.z), fmaf(a, b.w, c.w));
}

// bf16 pack (round-to-nearest-even) / unpack-as-bit-ops
__device__ __forceinline__ unsigned bf16rtne(float f) {
    unsigned u = __float_as_uint(f);
    return (u + 0x7fffu + ((u >> 16) & 1u)) >> 16;
}
__device__ __forceinline__ unsigned packbf2(float a, float b) {
    return bf16rtne(a) | (bf16rtne(b) << 16);
}
__device__ __forceinline__ float4 unpackbf4(uint2 r) {
    return make_float4(__uint_as_float(r.x << 16),
                       __uint_as_float(r.x & 0xffff0000u),
                       __uint_as_float(r.y << 16),
                       __uint_as_float(r.y & 0xffff0000u));
}

// ---------------------------------------------------------------------------
// init: cnt[i]=0; first 64 blocks zero BN partial buckets (2 layers x 64
// replicas x 128); block 0 detects edge_index dtype (int64 high words all 0).
// ---------------------------------------------------------------------------
__global__ __launch_bounds__(256) void init_kernel(
    const unsigned* __restrict__ w, int* __restrict__ flag,
    int* __restrict__ cnt, float* __restrict__ parts, int N) {
    int i = blockIdx.x * 256 + threadIdx.x;
    if (i < N) cnt[i] = 0;
    if (blockIdx.x < 64) parts[blockIdx.x * 256 + threadIdx.x] = 0.0f;
    if (blockIdx.x == 0 && threadIdx.x < 64) {
        unsigned long long ok = __ballot(w[2 * threadIdx.x + 1] == 0u);
        if (threadIdx.x == 0) *flag = (ok == ~0ull);
    }
}

// count edges per dst; seq[e] = arrival slot within its dst row (the atomic's
// return value). 8 independent atomics in flight per thread.
__global__ __launch_bounds__(256) void count_seq_kernel(
    const void* __restrict__ ei, const int* __restrict__ flag,
    int* __restrict__ cnt, int* __restrict__ seq, int E) {
    int is64 = *flag;
    int T = gridDim.x * 256;
    int i = blockIdx.x * 256 + threadIdx.x;
#pragma unroll
    for (int u = 0; u < 8; ++u) {
        int e = i + u * T;
        if (e < E) {
            int dst = edge_idx(ei, is64, (long long)E + e);
            seq[e] = atomicAdd(&cnt[dst], 1);
        }
    }
}

// ---- exclusive scan over cnt[N] -> rowptr (3-level; N <= 256*256) ----------
__global__ __launch_bounds__(256) void scan1_kernel(const int* __restrict__ cnt,
                                                    int* __restrict__ excl,
                                                    int* __restrict__ bsum, int N) {
    __shared__ int tmp[256];
    int i = blockIdx.x * 256 + threadIdx.x;
    int v = (i < N) ? cnt[i] : 0;
    tmp[threadIdx.x] = v;
    __syncthreads();
    for (int off = 1; off < 256; off <<= 1) {
        int t = (threadIdx.x >= off) ? tmp[threadIdx.x - off] : 0;
        __syncthreads();
        tmp[threadIdx.x] += t;
        __syncthreads();
    }
    if (i < N) excl[i] = tmp[threadIdx.x] - v;
    if (threadIdx.x == 255) bsum[blockIdx.x] = tmp[255];
}

__global__ __launch_bounds__(256) void scan2_kernel(int* __restrict__ bsum, int nb) {
    __shared__ int tmp[256];
    int i = threadIdx.x;
    int v = (i < nb) ? bsum[i] : 0;
    tmp[i] = v;
    __syncthreads();
    for (int off = 1; off < 256; off <<= 1) {
        int t = (i >= off) ? tmp[i - off] : 0;
        __syncthreads();
        tmp[i] += t;
        __syncthreads();
    }
    if (i < nb) bsum[i] = tmp[i] - v;  // exclusive block offsets, in place
}

__global__ void scan3_kernel(const int* __restrict__ excl,
                             const int* __restrict__ bsum,
                             int* __restrict__ rowptr, int N, int E) {
    int i = blockIdx.x * 256 + threadIdx.x;
    if (i < N) rowptr[i] = excl[i] + bsum[blockIdx.x];
    if (i == 0) rowptr[N] = E;
}

// csr[rowptr[dst]+seq[e]] = (src, ew-bits) — no atomics, plain writes
__global__ __launch_bounds__(256) void scatter_csr_kernel(
    const void* __restrict__ ei, const float* __restrict__ ew,
    const int* __restrict__ flag, const int* __restrict__ rowptr,
    const int* __restrict__ seq, int2* __restrict__ csr, int E) {
    int is64 = *flag;
    int T = gridDim.x * 256;
    int i = blockIdx.x * 256 + threadIdx.x;
#pragma unroll
    for (int u = 0; u < 2; ++u) {
        int e = i + u * T;
        if (e < E) {
            int src = edge_idx(ei, is64, e);
            int dst = edge_idx(ei, is64, (long long)E + e);
            int pos = rowptr[dst] + seq[e];
            csr[pos] = make_int2(src, __float_as_int(ew[e]));
        }
    }
}

// deg[n] = 1 + sum ew over row; 8 lanes per node, shfl reduce
__global__ __launch_bounds__(256) void deg_inv_kernel(
    const int* __restrict__ rowptr, const int2* __restrict__ csr,
    float* __restrict__ dinv, float* __restrict__ invdeg, int N) {
    int t = blockIdx.x * 256 + threadIdx.x;
    int n = t >> 3, l = t & 7;
    if (n >= N) return;
    int b = rowptr[n], e = rowptr[n + 1];
    float d = 0.0f;
    for (int k = b + l; k < e; k += 8) d += __int_as_float(csr[k].y);
    d += __shfl_xor(d, 1);
    d += __shfl_xor(d, 2);
    d += __shfl_xor(d, 4);
    if (l == 0) {
        d += 1.0f;
        dinv[n]   = rsqrtf(d);
        invdeg[n] = 1.0f / d;
    }
}

// edge-parallel, coalesced fold: csr[k].y = ew -> dinv[src]*ew
// (dinv[dst] is applied once per node in the gather epilogue)
__global__ __launch_bounds__(256) void fold_kernel(int2* __restrict__ csr,
                                                   const float* __restrict__ dinv,
                                                   int E) {
    int T = gridDim.x * 256;
    int i = blockIdx.x * 256 + threadIdx.x;
#pragma unroll
    for (int u = 0; u < 2; ++u) {
        int e = i + u * T;
        if (e < E) {
            int2 v = csr[e];
            csr[e].y = __float_as_int(dinv[v.x] * __int_as_float(v.y));
        }
    }
}

// ---------------------------------------------------------------------------
// out_bf[i][c] = bf16( sum_k in'[i][k] * W[k][c] ), in' = affine? relu : id
// 64 rows/block; thread = (rowgroup rg of 4 rows, colquad q of 4 cols).
// ---------------------------------------------------------------------------
__global__ __launch_bounds__(256) void gemm64_kernel(
    const float* __restrict__ in, const float* __restrict__ W,
    const float* __restrict__ scale, const float* __restrict__ shift,
    uint2* __restrict__ out_bf, int N, int affine) {
    __shared__ float4 Ws4[64][16];      // W[k][c] as float4 over c
    __shared__ float xs[64][65];        // padded: breaks bank conflicts
    __shared__ float sA[64], sS[64];
    int tid = threadIdx.x;
    const float4* W4 = (const float4*)W;
    for (int j = tid; j < 1024; j += 256) Ws4[j >> 4][j & 15] = W4[j];
    if (affine && tid < 64) { sA[tid] = scale[tid]; sS[tid] = shift[tid]; }
    __syncthreads();

    int rowBase = blockIdx.x * 64;
    for (int j = tid; j < 1024; j += 256) {
        int r = j >> 4, q = j & 15;
        int row = rowBase + r;
        float4 v = make_float4(0.f, 0.f, 0.f, 0.f);
        if (row < N) {
            v = ((const float4*)in)[(size_t)row * 16 + q];
            if (affine) {
                int c = q * 4;
                v.x = fmaxf(fmaf(v.x, sA[c + 0], sS[c + 0]), 0.f);
                v.y = fmaxf(fmaf(v.y, sA[c + 1], sS[c + 1]), 0.f);
                v.z = fmaxf(fmaf(v.z, sA[c + 2], sS[c + 2]), 0.f);
                v.w = fmaxf(fmaf(v.w, sA[c + 3], sS[c + 3]), 0.f);
            }
        }
        xs[r][q * 4 + 0] = v.x;
        xs[r][q * 4 + 1] = v.y;
        xs[r][q * 4 + 2] = v.z;
        xs[r][q * 4 + 3] = v.w;
    }
    __syncthreads();

    int q = tid & 15, rg = tid >> 4;
    int r0 = rg * 4;
    float4 a0 = make_float4(0.f, 0.f, 0.f, 0.f), a1 = a0, a2 = a0, a3 = a0;
#pragma unroll 4
    for (int k = 0; k < 64; ++k) {
        float4 wv = Ws4[k][q];
        a0 = f4fma(xs[r0 + 0][k], wv, a0);
        a1 = f4fma(xs[r0 + 1][k], wv, a1);
        a2 = f4fma(xs[r0 + 2][k], wv, a2);
        a3 = f4fma(xs[r0 + 3][k], wv, a3);
    }
    int row = rowBase + r0;
    if (row + 0 < N) out_bf[(size_t)(row + 0) * 16 + q] = make_uint2(packbf2(a0.x, a0.y), packbf2(a0.z, a0.w));
    if (row + 1 < N) out_bf[(size_t)(row + 1) * 16 + q] = make_uint2(packbf2(a1.x, a1.y), packbf2(a1.z, a1.w));
    if (row + 2 < N) out_bf[(size_t)(row + 2) * 16 + q] = make_uint2(packbf2(a2.x, a2.y), packbf2(a2.z, a2.w));
    if (row + 3 < N) out_bf[(size_t)(row + 3) * 16 + q] = make_uint2(packbf2(a3.x, a3.y), packbf2(a3.z, a3.w));
}

// ---------------------------------------------------------------------------
// agg[n] = dinv[n]*sum_k w'[k]*h[src[k]] + invdeg[n]*h[n] + bias  (w'=dinv*ew)
// + fused BN column stats -> 64-replica atomic buckets.
// One wave per node; edges in 16-wide chunks: each 16-lane subgroup
// burst-loads 4 csr entries, then 4 h-rows (all independent) -> ~8
// outstanding loads per wave instead of 1 (the R5 latency limiter).
// ---------------------------------------------------------------------------
__global__ __launch_bounds__(256) void gather_agg_kernel(
    const uint2* __restrict__ h2, const int* __restrict__ rowptr,
    const int2* __restrict__ csr, const float* __restrict__ dinv,
    const float* __restrict__ invdeg, const float* __restrict__ bias,
    float* __restrict__ agg, float* __restrict__ parts, int N) {
    int tid = threadIdx.x;
    int wave = tid >> 6, lane = tid & 63;
    int sub = lane >> 4, sl = lane & 15;
    float4 bv = ((const float4*)bias)[sl];
    float4 bnS = make_float4(0.f, 0.f, 0.f, 0.f), bnQ = bnS;

    int n = blockIdx.x * 4 + wave;   // one node per wave
    if (n < N) {
        int beg = rowptr[n], end = rowptr[n + 1];
        // independent early loads (hide under the edge loop)
        uint2 selfr = h2[(size_t)n * 16 + sl];
        float dn = dinv[n], idg = invdeg[n];

        float4 accE = make_float4(0.f, 0.f, 0.f, 0.f);
        for (int k = beg; k < end; k += 16) {
            int srcs[4]; float w[4];
#pragma unroll
            for (int j = 0; j < 4; ++j) {           // burst 1: csr entries
                int idx = k + sub + 4 * j;          // subgroup-uniform predicate
                if (idx < end) {
                    int2 ed = csr[idx];
                    srcs[j] = ed.x; w[j] = __int_as_float(ed.y);
                } else { srcs[j] = 0; w[j] = 0.f; }
            }
            uint2 hr[4];
#pragma unroll
            for (int j = 0; j < 4; ++j)             // burst 2: h rows
                hr[j] = (k + sub + 4 * j < end)
                          ? h2[(size_t)srcs[j] * 16 + sl] : make_uint2(0u, 0u);
#pragma unroll
            for (int j = 0; j < 4; ++j)             // burst 3: fma
                accE = f4fma(w[j], unpackbf4(hr[j]), accE);
        }
        // combine the 4 subgroup partials (xor over lane bits 4,5)
        accE.x += __shfl_xor(accE.x, 16); accE.y += __shfl_xor(accE.y, 16);
        accE.z += __shfl_xor(accE.z, 16); accE.w += __shfl_xor(accE.w, 16);
        accE.x += __shfl_xor(accE.x, 32); accE.y += __shfl_xor(accE.y, 32);
        accE.z += __shfl_xor(accE.z, 32); accE.w += __shfl_xor(accE.w, 32);

        if (sub == 0) {
            float4 self = unpackbf4(selfr);
            float4 tot = f4fma(idg, self, bv);
            tot = f4fma(dn, accE, tot);
            ((float4*)agg)[(size_t)n * 16 + sl] = tot;
            bnS.x += tot.x; bnS.y += tot.y; bnS.z += tot.z; bnS.w += tot.w;
            bnQ.x = fmaf(tot.x, tot.x, bnQ.x); bnQ.y = fmaf(tot.y, tot.y, bnQ.y);
            bnQ.z = fmaf(tot.z, tot.z, bnQ.z); bnQ.w = fmaf(tot.w, tot.w, bnQ.w);
        }
    }

    __shared__ float4 LS[4][16], LQ[4][16];
    if (sub == 0) { LS[wave][sl] = bnS; LQ[wave][sl] = bnQ; }
    __syncthreads();
    if (tid < 16) {
        float4 ts = LS[0][tid], tq = LQ[0][tid];
        for (int i = 1; i < 4; ++i) {
            float4 a = LS[i][tid], b = LQ[i][tid];
            ts.x += a.x; ts.y += a.y; ts.z += a.z; ts.w += a.w;
            tq.x += b.x; tq.y += b.y; tq.z += b.z; tq.w += b.w;
        }
        // replica bucket: [rep][ sum[64] | sq[64] ]
        float* P = parts + (size_t)(blockIdx.x & (BN_REPS - 1)) * 128;
        int c = tid * 4;
        unsafeAtomicAdd(&P[c + 0], ts.x);      unsafeAtomicAdd(&P[c + 1], ts.y);
        unsafeAtomicAdd(&P[c + 2], ts.z);      unsafeAtomicAdd(&P[c + 3], ts.w);
        unsafeAtomicAdd(&P[64 + c + 0], tq.x); unsafeAtomicAdd(&P[64 + c + 1], tq.y);
        unsafeAtomicAdd(&P[64 + c + 2], tq.z); unsafeAtomicAdd(&P[64 + c + 3], tq.w);
    }
}

// reduce replicas; a[c] = gamma*rsqrt(var+eps); s[c] = beta - mean*a
__global__ void bn_final_kernel(const float* __restrict__ parts,
                                const float* __restrict__ gamma,
                                const float* __restrict__ beta,
                                float* __restrict__ a, float* __restrict__ s,
                                float invN) {
    int c = threadIdx.x;
    if (c < 64) {
        float sm = 0.f, sq = 0.f;
        for (int r = 0; r < BN_REPS; ++r) {
            sm += parts[r * 128 + c];
            sq += parts[r * 128 + 64 + c];
        }
        float m = sm * invN;
        float var = fmaxf(sq * invN - m * m, 0.0f);
        float aa = gamma[c] * rsqrtf(var + BN_EPS);
        a[c] = aa;
        s[c] = beta[c] - m * aa;
    }
}

// out = relu(agg*a + s + x), float4
__global__ void final_out_kernel(const float* __restrict__ agg,
                                 const float* __restrict__ a,
                                 const float* __restrict__ s,
                                 const float* __restrict__ x,
                                 float* __restrict__ out, int nquads) {
    int gid = blockIdx.x * 256 + threadIdx.x;
    if (gid < nquads) {
        int q = gid & 15;
        float4 av = ((const float4*)a)[q], sv = ((const float4*)s)[q];
        float4 g = ((const float4*)agg)[gid], xv = ((const float4*)x)[gid];
        float4 o;
        o.x = fmaxf(fmaf(g.x, av.x, sv.x) + xv.x, 0.f);
        o.y = fmaxf(fmaf(g.y, av.y, sv.y) + xv.y, 0.f);
        o.z = fmaxf(fmaf(g.z, av.z, sv.z) + xv.z, 0.f);
        o.w = fmaxf(fmaf(g.w, av.w, sv.w) + xv.w, 0.f);
        ((float4*)out)[gid] = o;
    }
}

extern "C" void kernel_launch(void* const* d_in, const int* in_sizes, int n_in,
                              void* d_out, int out_size, void* d_ws, size_t ws_size,
                              hipStream_t stream) {
    const float* x      = (const float*)d_in[0];
    const void*  ei     = d_in[1];           // int64 or int32, detected on device
    const float* ew     = (const float*)d_in[2];
    const float* W1     = (const float*)d_in[3];
    const float* b1     = (const float*)d_in[4];
    const float* gamma1 = (const float*)d_in[5];
    const float* beta1  = (const float*)d_in[6];
    const float* W2     = (const float*)d_in[7];
    const float* b2     = (const float*)d_in[8];
    const float* gamma2 = (const float*)d_in[9];
    const float* beta2  = (const float*)d_in[10];
    float* out = (float*)d_out;

    const int N = in_sizes[0] / FEAT;
    const int E = in_sizes[2];

    // workspace layout (256B-aligned chunks)
    char* ws = (char*)d_ws;
    size_t off = 0;
    auto alloc = [&](size_t bytes) {
        size_t o = off;
        off += (bytes + 255) & ~(size_t)255;
        return (void*)(ws + o);
    };
    int*   flag   = (int*)  alloc(256);
    int*   cnt    = (int*)  alloc((size_t)N * 4);
    int*   rowptr = (int*)  alloc((size_t)(N + 1) * 4);
    int*   seq    = (int*)  alloc((size_t)E * 4);
    int*   excl   = (int*)  alloc((size_t)N * 4);
    int*   bsum   = (int*)  alloc(256 * 4);
    float* dinv   = (float*)alloc((size_t)N * 4);
    float* invdeg = (float*)alloc((size_t)N * 4);
    float* parts  = (float*)alloc(2 * BN_REPS * 128 * 4);  // 2 layers of buckets
    float* ab     = (float*)alloc(256 * 4);                // a1 s1 a2 s2
    int2*  csr    = (int2*) alloc((size_t)E * 8);
    uint2* h_bf   = (uint2*)alloc((size_t)N * 16 * 8);     // N x 64 bf16
    float* agg    = (float*)alloc((size_t)N * FEAT * 4);

    const int nblkN  = (N + 255) / 256;
    const int nblkN8 = (N * 8 + 255) / 256;
    const int nblkE8 = (E + 2047) / 2048;
    const int nblkE2 = (E + 511) / 512;
    const int nblkQ  = (N * 16 + 255) / 256;
    const int nblkG  = (N + 63) / 64;
    const int nblkA  = (N + 3) / 4;   // one wave per node, 4 waves/block

    // ---- CSR build (shared by both layers) ----
    init_kernel<<<nblkN, 256, 0, stream>>>((const unsigned*)ei, flag, cnt, parts, N);
    count_seq_kernel<<<nblkE8, 256, 0, stream>>>(ei, flag, cnt, seq, E);
    scan1_kernel<<<nblkN, 256, 0, stream>>>(cnt, excl, bsum, N);
    scan2_kernel<<<1, 256, 0, stream>>>(bsum, nblkN);
    scan3_kernel<<<nblkN, 256, 0, stream>>>(excl, bsum, rowptr, N, E);
    scatter_csr_kernel<<<nblkE2, 256, 0, stream>>>(ei, ew, flag, rowptr, seq, csr, E);
    deg_inv_kernel<<<nblkN8, 256, 0, stream>>>(rowptr, csr, dinv, invdeg, N);
    fold_kernel<<<nblkE2, 256, 0, stream>>>(csr, dinv, E);

    // ---- layer 1 ----
    gemm64_kernel<<<nblkG, 256, 0, stream>>>(x, W1, nullptr, nullptr, h_bf, N, 0);
    gather_agg_kernel<<<nblkA, 256, 0, stream>>>(h_bf, rowptr, csr, dinv,
                                                 invdeg, b1, agg, parts, N);
    bn_final_kernel<<<1, 64, 0, stream>>>(parts, gamma1, beta1,
                                          ab, ab + 64, 1.0f / (float)N);

    // ---- layer 2 (gemm fuses BN1 apply + relu on input load) ----
    gemm64_kernel<<<nblkG, 256, 0, stream>>>(agg, W2, ab, ab + 64, h_bf, N, 1);
    gather_agg_kernel<<<nblkA, 256, 0, stream>>>(h_bf, rowptr, csr, dinv,
                                                 invdeg, b2, agg,
                                                 parts + BN_REPS * 128, N);
    bn_final_kernel<<<1, 64, 0, stream>>>(parts + BN_REPS * 128, gamma2, beta2,
                                          ab + 128, ab + 192, 1.0f / (float)N);

    // ---- residual + relu ----
    final_out_kernel<<<nblkQ, 256, 0, stream>>>(agg, ab + 128, ab + 192, x,
                                                out, N * 16);
}